// Round 3
// baseline (654.114 us; speedup 1.0000x reference)
//
#include <hip/hip_runtime.h>

#define B_ 4
#define T_ 1024
#define C_ 768
#define H_ 12
#define D_ 64
#define W_ 4

typedef unsigned short u16;

__device__ __forceinline__ float b2f(u16 u) {
    return __uint_as_float(((unsigned)u) << 16);
}
__device__ __forceinline__ u16 f2b(float f) {
    unsigned u = __float_as_uint(f);
    u += 0x7fffu + ((u >> 16) & 1u);   // round-to-nearest-even
    return (u16)(u >> 16);
}

// ---------------------------------------------------------------------------
// Tiled GEMM: dst[b,o,t] = (sum_c W[o,c] * src[b,c,t] + bias[o]) * scale
// All external tensors fp32. src layout (B, C, T).
// DST_BF16_QKV=1: store bf16 to (B,H,T,d) ws tensor (scale applied).
// DST_BF16_QKV=0: store fp32 to (B,C,T) d_out.
// ---------------------------------------------------------------------------
template <bool DST_BF16_QKV>
__global__ __launch_bounds__(256) void proj_kernel(
    const float* __restrict__ src, const float* __restrict__ w,
    const float* __restrict__ bias, void* __restrict__ dstv, float scale)
{
    __shared__ __align__(16) float w_s[16][68];
    __shared__ __align__(16) float x_s[16][68];

    const int tid = threadIdx.x;
    const int tx = tid & 15, ty = tid >> 4;
    const int t0 = blockIdx.x * 64;
    const int o0 = blockIdx.y * 64;
    const int b  = blockIdx.z;

    const int oo = tid >> 2, c4 = (tid & 3) * 4;      // W staging map
    const int xc = tid >> 4, xt4 = (tid & 15) * 4;    // X staging map

    float acc[4][4] = {};

    for (int c0 = 0; c0 < C_; c0 += 16) {
        // stage W transposed: w_s[cc][oo]
        {
            float4 wv = *(const float4*)(w + (size_t)(o0 + oo) * C_ + c0 + c4);
            w_s[c4 + 0][oo] = wv.x;
            w_s[c4 + 1][oo] = wv.y;
            w_s[c4 + 2][oo] = wv.z;
            w_s[c4 + 3][oo] = wv.w;
        }
        // stage X: x_s[cc][tt] (coalesced over t)
        {
            float4 xv = *(const float4*)(src + ((size_t)b * C_ + c0 + xc) * T_ + t0 + xt4);
            x_s[xc][xt4 + 0] = xv.x;
            x_s[xc][xt4 + 1] = xv.y;
            x_s[xc][xt4 + 2] = xv.z;
            x_s[xc][xt4 + 3] = xv.w;
        }
        __syncthreads();
        #pragma unroll
        for (int cc = 0; cc < 16; ++cc) {
            const float4 av = *(const float4*)&w_s[cc][ty * 4];
            const float4 bv = *(const float4*)&x_s[cc][tx * 4];
            const float aa[4] = {av.x, av.y, av.z, av.w};
            const float bb[4] = {bv.x, bv.y, bv.z, bv.w};
            #pragma unroll
            for (int ii = 0; ii < 4; ++ii)
                #pragma unroll
                for (int jj = 0; jj < 4; ++jj)
                    acc[ii][jj] = fmaf(aa[ii], bb[jj], acc[ii][jj]);
        }
        __syncthreads();
    }

    if (DST_BF16_QKV) {
        u16* dst = (u16*)dstv;
        const int h = o0 >> 6;                 // o0 is a multiple of 64 = D_
        #pragma unroll
        for (int ii = 0; ii < 4; ++ii) {
            const int dd = ty * 4 + ii;        // head-dim index
            const float bs = bias[o0 + dd];
            #pragma unroll
            for (int jj = 0; jj < 4; ++jj) {
                const int t = t0 + tx * 4 + jj;
                dst[(((size_t)b * H_ + h) * T_ + t) * D_ + dd] =
                    f2b((acc[ii][jj] + bs) * scale);
            }
        }
    } else {
        float* dst = (float*)dstv;
        #pragma unroll
        for (int ii = 0; ii < 4; ++ii) {
            const int oc = o0 + ty * 4 + ii;
            const float bs = bias[oc];
            float4 st;
            st.x = acc[ii][0] + bs;
            st.y = acc[ii][1] + bs;
            st.z = acc[ii][2] + bs;
            st.w = acc[ii][3] + bs;
            *(float4*)(dst + ((size_t)b * C_ + oc) * T_ + t0 + tx * 4) = st;
        }
    }
}

// ---------------------------------------------------------------------------
// Flash attention with windowed relative-position bias (k and v).
// One block per (b, h, 64-row query tile). q,k,v: bf16 (B,H,T,d) in ws.
// emb_rel_k / emb_rel_v: fp32 (9, 64) external.
// att out: fp32 (B, C, T) in ws (channel = h*64+dd).
// ---------------------------------------------------------------------------
__global__ __launch_bounds__(256) void attn_kernel(
    const u16* __restrict__ qw, const u16* __restrict__ kw, const u16* __restrict__ vw,
    const float* __restrict__ erk, const float* __restrict__ erv,
    float* __restrict__ att)
{
    __shared__ __align__(16) float q_s[64][64];   // [dd][i]
    __shared__ __align__(16) float k_s[64][68];   // [dd][j]
    __shared__ __align__(16) u16   v_s[64][68];   // [j][dd] raw bf16 bits
    __shared__ __align__(16) float p_s[64][68];   // [j][i]
    __shared__ __align__(16) float erk_s[9][64];
    __shared__ __align__(16) float erv_s[9][64];
    __shared__ float qrel_s[64][9];               // q_i . emb_k[r]
    __shared__ float m_s[64], l_s[64];

    const int tid = threadIdx.x;
    const int tx = tid & 15, ty = tid >> 4;
    const int it0 = blockIdx.x * 64;
    const int h = blockIdx.y, b = blockIdx.z;
    const int bh = b * H_ + h;

    const u16* qp = qw + (size_t)bh * T_ * D_;
    const u16* kp = kw + (size_t)bh * T_ * D_;
    const u16* vp = vw + (size_t)bh * T_ * D_;

    if (tid < 64) { m_s[tid] = -1e30f; l_s[tid] = 0.f; }

    const int sr = tid >> 2, sd4 = (tid & 3) * 4;

    // stage Q transposed (once per block)
    {
        const u16* qrow = qp + (size_t)(it0 + sr) * D_;
        #pragma unroll
        for (int rep = 0; rep < 4; ++rep) {
            const int dd = sd4 + rep * 16;
            ushort4 u = *(const ushort4*)(qrow + dd);
            q_s[dd + 0][sr] = b2f(u.x);
            q_s[dd + 1][sr] = b2f(u.y);
            q_s[dd + 2][sr] = b2f(u.z);
            q_s[dd + 3][sr] = b2f(u.w);
        }
    }
    for (int idx = tid; idx < 9 * 64; idx += 256) {
        erk_s[idx >> 6][idx & 63] = erk[idx];
        erv_s[idx >> 6][idx & 63] = erv[idx];
    }
    __syncthreads();

    // qrel[i][r] = sum_d q[i][d] * emb_k[r][d]  (q already scaled by 1/8)
    for (int idx = tid; idx < 9 * 64; idx += 256) {
        const int i = idx & 63, r = idx >> 6;
        float s = 0.f;
        for (int dd = 0; dd < 64; ++dd) s += q_s[dd][i] * erk_s[r][dd];
        qrel_s[i][r] = s;
    }

    float o_acc[4][4] = {};

    for (int jt = 0; jt < T_; jt += 64) {
        __syncthreads();   // protect k_s/v_s writers (and first iter: qrel_s)
        {
            const u16* krow = kp + (size_t)(jt + sr) * D_;
            const u16* vrow = vp + (size_t)(jt + sr) * D_;
            #pragma unroll
            for (int rep = 0; rep < 4; ++rep) {
                const int dd = sd4 + rep * 16;
                ushort4 ku = *(const ushort4*)(krow + dd);
                k_s[dd + 0][sr] = b2f(ku.x);
                k_s[dd + 1][sr] = b2f(ku.y);
                k_s[dd + 2][sr] = b2f(ku.z);
                k_s[dd + 3][sr] = b2f(ku.w);
                *(ushort4*)&v_s[sr][dd] = *(const ushort4*)(vrow + dd);
            }
        }
        __syncthreads();

        // scores: s[ii][jj] = q_i . k_j
        float s[4][4] = {};
        #pragma unroll 16
        for (int dd = 0; dd < 64; ++dd) {
            const float4 qv = *(const float4*)&q_s[dd][ty * 4];
            const float4 kv = *(const float4*)&k_s[dd][tx * 4];
            const float qa[4] = {qv.x, qv.y, qv.z, qv.w};
            const float kb[4] = {kv.x, kv.y, kv.z, kv.w};
            #pragma unroll
            for (int ii = 0; ii < 4; ++ii)
                #pragma unroll
                for (int jj = 0; jj < 4; ++jj)
                    s[ii][jj] = fmaf(qa[ii], kb[jj], s[ii][jj]);
        }

        // windowed rel-k bias: r = (j - i) + 4 in [0, 8]
        const int diag = jt - it0 + 4;
        #pragma unroll
        for (int ii = 0; ii < 4; ++ii) {
            const int il = ty * 4 + ii;
            #pragma unroll
            for (int jj = 0; jj < 4; ++jj) {
                const int r = diag + tx * 4 + jj - il;
                if (r >= 0 && r <= 8) s[ii][jj] += qrel_s[il][r];
            }
        }

        // online softmax (rows live within one wave; reduce over tx lanes)
        float alpha[4];
        #pragma unroll
        for (int ii = 0; ii < 4; ++ii) {
            float tm = fmaxf(fmaxf(s[ii][0], s[ii][1]), fmaxf(s[ii][2], s[ii][3]));
            #pragma unroll
            for (int mask = 1; mask < 16; mask <<= 1)
                tm = fmaxf(tm, __shfl_xor(tm, mask));
            const int il = ty * 4 + ii;
            const float mo = m_s[il];
            const float nm = fmaxf(mo, tm);
            float rs = 0.f;
            #pragma unroll
            for (int jj = 0; jj < 4; ++jj) {
                s[ii][jj] = __expf(s[ii][jj] - nm);
                rs += s[ii][jj];
            }
            #pragma unroll
            for (int mask = 1; mask < 16; mask <<= 1)
                rs += __shfl_xor(rs, mask);
            alpha[ii] = __expf(mo - nm);
            if (tx == 0) {
                m_s[il] = nm;
                l_s[il] = l_s[il] * alpha[ii] + rs;
            }
        }

        // P transpose through LDS: p_s[j][i]
        #pragma unroll
        for (int ii = 0; ii < 4; ++ii)
            #pragma unroll
            for (int jj = 0; jj < 4; ++jj)
                p_s[tx * 4 + jj][ty * 4 + ii] = s[ii][jj];

        // rescale accumulator
        #pragma unroll
        for (int ii = 0; ii < 4; ++ii)
            #pragma unroll
            for (int jj = 0; jj < 4; ++jj)
                o_acc[ii][jj] *= alpha[ii];

        __syncthreads();   // make p_s visible

        // PV: o[i][dd] += sum_j p[i][j] * v[j][dd]
        #pragma unroll 16
        for (int j = 0; j < 64; ++j) {
            const float4 pv = *(const float4*)&p_s[j][ty * 4];
            const ushort4 vu = *(const ushort4*)&v_s[j][tx * 4];
            const float pa[4] = {pv.x, pv.y, pv.z, pv.w};
            const float vb[4] = {b2f(vu.x), b2f(vu.y), b2f(vu.z), b2f(vu.w)};
            #pragma unroll
            for (int ii = 0; ii < 4; ++ii)
                #pragma unroll
                for (int jj = 0; jj < 4; ++jj)
                    o_acc[ii][jj] = fmaf(pa[ii], vb[jj], o_acc[ii][jj]);
        }

        // windowed rel-v: o[i][dd] += p[i][j] * emb_v[j-i+4][dd]
        #pragma unroll
        for (int ii = 0; ii < 4; ++ii) {
            const int il = ty * 4 + ii;
            const int gi = it0 + il;
            #pragma unroll
            for (int r = 0; r <= 8; ++r) {
                const int lj = gi + r - 4 - jt;
                if (lj >= 0 && lj < 64) {
                    const float pr = p_s[lj][il];
                    #pragma unroll
                    for (int jj = 0; jj < 4; ++jj)
                        o_acc[ii][jj] = fmaf(pr, erv_s[r][tx * 4 + jj], o_acc[ii][jj]);
                }
            }
        }
    }

    // normalize and store fp32 att in (B, C, T): channel = h*64 + dd, time = i
    float inv[4];
    #pragma unroll
    for (int ii = 0; ii < 4; ++ii) inv[ii] = 1.f / l_s[ty * 4 + ii];

    #pragma unroll
    for (int jj = 0; jj < 4; ++jj) {
        float4 st;
        st.x = o_acc[0][jj] * inv[0];
        st.y = o_acc[1][jj] * inv[1];
        st.z = o_acc[2][jj] * inv[2];
        st.w = o_acc[3][jj] * inv[3];
        *(float4*)(att + ((size_t)b * C_ + h * D_ + tx * 4 + jj) * T_ + it0 + ty * 4) = st;
    }
}

extern "C" void kernel_launch(void* const* d_in, const int* in_sizes, int n_in,
                              void* d_out, int out_size, void* d_ws, size_t ws_size,
                              hipStream_t stream) {
    const float* x   = (const float*)d_in[0];
    const float* w_q = (const float*)d_in[1];
    const float* b_q = (const float*)d_in[2];
    const float* w_k = (const float*)d_in[3];
    const float* b_k = (const float*)d_in[4];
    const float* w_v = (const float*)d_in[5];
    const float* b_v = (const float*)d_in[6];
    const float* w_o = (const float*)d_in[7];
    const float* b_o = (const float*)d_in[8];
    const float* erk = (const float*)d_in[9];
    const float* erv = (const float*)d_in[10];

    const size_t N = (size_t)B_ * C_ * T_;   // 3,145,728
    u16*   q_ws = (u16*)d_ws;
    u16*   k_ws = q_ws + N;
    u16*   v_ws = q_ws + 2 * N;
    float* a_ws = (float*)(q_ws + 3 * N);    // fp32 attention out (B,C,T)
    float* out  = (float*)d_out;

    dim3 blk(256, 1, 1);
    dim3 gproj(T_ / 64, C_ / 64, B_);

    proj_kernel<true><<<gproj, blk, 0, stream>>>(x, w_q, b_q, q_ws, 0.125f);
    proj_kernel<true><<<gproj, blk, 0, stream>>>(x, w_k, b_k, k_ws, 1.0f);
    proj_kernel<true><<<gproj, blk, 0, stream>>>(x, w_v, b_v, v_ws, 1.0f);

    attn_kernel<<<dim3(T_ / 64, H_, B_), blk, 0, stream>>>(q_ws, k_ws, v_ws, erk, erv, a_ws);

    proj_kernel<false><<<gproj, blk, 0, stream>>>(a_ws, w_o, b_o, out, 1.0f);
}

// Round 4
// 406.331 us; speedup vs baseline: 1.6098x; 1.6098x over previous
//
#include <hip/hip_runtime.h>

#define B_ 4
#define T_ 1024
#define C_ 768
#define H_ 12
#define D_ 64

typedef unsigned short u16;
typedef __attribute__((ext_vector_type(8))) short b16x8;   // 8 bf16 (4 VGPRs)
typedef __attribute__((ext_vector_type(4))) float f32x4;   // MFMA C/D

__device__ __forceinline__ float b2f(u16 u) {
    return __uint_as_float(((unsigned)u) << 16);
}
__device__ __forceinline__ u16 f2b(float f) {
    unsigned u = __float_as_uint(f);
    u += 0x7fffu + ((u >> 16) & 1u);   // round-to-nearest-even
    return (u16)(u >> 16);
}

// async global->LDS, 16B per lane; LDS dest = wave-uniform base + lane*16
__device__ __forceinline__ void g2l16(const u16* g, u16* l) {
    __builtin_amdgcn_global_load_lds(
        (const __attribute__((address_space(1))) unsigned int*)g,
        (__attribute__((address_space(3))) unsigned int*)l, 16, 0, 0);
}

// ---------------------------------------------------------------------------
// fp32 -> bf16 weight convert (4 matrices concatenated into wb)
// ---------------------------------------------------------------------------
__global__ __launch_bounds__(256) void convw_kernel(
    const float* __restrict__ w0, const float* __restrict__ w1,
    const float* __restrict__ w2, const float* __restrict__ w3,
    u16* __restrict__ o)
{
    const float* src = blockIdx.y == 0 ? w0 : blockIdx.y == 1 ? w1 :
                       blockIdx.y == 2 ? w2 : w3;
    u16* dst = o + (size_t)blockIdx.y * C_ * C_;
    const int i = (blockIdx.x * 256 + threadIdx.x) * 4;
    float4 v = *(const float4*)(src + i);
    ushort4 st = {f2b(v.x), f2b(v.y), f2b(v.z), f2b(v.w)};
    *(ushort4*)(dst + i) = st;
}

// ---------------------------------------------------------------------------
// x (B,C,T) fp32 -> xb (B,T,C) bf16 (transpose through LDS tile)
// ---------------------------------------------------------------------------
__global__ __launch_bounds__(256) void convx_kernel(
    const float* __restrict__ x, u16* __restrict__ xb)
{
    __shared__ u16 tile[64][68];
    const int tid = threadIdx.x;
    const int t0 = blockIdx.x * 64, c0 = blockIdx.y * 64, b = blockIdx.z;
    #pragma unroll
    for (int p = 0; p < 4; ++p) {
        const int cc = p * 16 + (tid >> 4);
        const int t4 = (tid & 15) * 4;
        float4 v = *(const float4*)(x + ((size_t)b * C_ + c0 + cc) * T_ + t0 + t4);
        tile[t4 + 0][cc] = f2b(v.x);
        tile[t4 + 1][cc] = f2b(v.y);
        tile[t4 + 2][cc] = f2b(v.z);
        tile[t4 + 3][cc] = f2b(v.w);
    }
    __syncthreads();
    #pragma unroll
    for (int p = 0; p < 4; ++p) {
        const int tt = p * 16 + (tid >> 4);
        const int c4 = (tid & 15) * 4;
        ushort4 st = *(const ushort4*)&tile[tt][c4];
        *(ushort4*)(xb + ((size_t)b * T_ + t0 + tt) * C_ + c0 + c4) = st;
    }
}

// ---------------------------------------------------------------------------
// Fused QKV projection, MFMA bf16. C[o][t] = sum_c W[o][c] * X^T[t][c].
// Tile 128(o) x 128(t), 4 waves (2x2), each 64x64 via 4x4 16x16x32 MFMA.
// A = wb (mat-selected, row-major o,c), B = xb (B,T,C, c contiguous).
// Epilogue: bf16 (B,H,T,d) with bias+scale.
// k-block XOR swizzle: LDS row r slot s holds k-block s^((r>>1)&3).
// ---------------------------------------------------------------------------
__global__ __launch_bounds__(256) void qkv_mfma_kernel(
    const u16* __restrict__ wb, const u16* __restrict__ xb,
    const float* __restrict__ b_q, const float* __restrict__ b_k,
    const float* __restrict__ b_v,
    u16* __restrict__ q_ws, u16* __restrict__ k_ws, u16* __restrict__ v_ws)
{
    __shared__ u16 a_s[128 * 32];
    __shared__ u16 b_s[128 * 32];

    const int tid = threadIdx.x;
    const int wv = tid >> 6, lane = tid & 63;
    const int lo = lane & 15, quad = lane >> 4;
    const int wm = wv >> 1, wn = wv & 1;
    const int swz = (lo >> 1) & 3;
    const int srow = lane >> 2;                       // staging row within instr
    const int skb  = (lane & 3) ^ ((lane >> 3) & 3);  // staged k-block (swizzled)

    const int t0 = blockIdx.x * 128;
    const int mat = blockIdx.y / 6, oy = blockIdx.y % 6;
    const int o0 = oy * 128;
    const int b  = blockIdx.z;

    const u16* A = wb + (size_t)mat * C_ * C_;
    const float* bias = mat == 0 ? b_q : (mat == 1 ? b_k : b_v);
    u16* dst = mat == 0 ? q_ws : (mat == 1 ? k_ws : v_ws);
    const float scale = mat == 0 ? 0.125f : 1.0f;

    const size_t bT0 = (size_t)b * T_ + t0;

    f32x4 acc[4][4] = {};

    for (int kk = 0; kk < C_; kk += 32) {
        __syncthreads();
        #pragma unroll
        for (int ia = 0; ia < 2; ++ia) {           // A: 8 instrs, 2/wave
            const int row0 = (wv * 2 + ia) * 16;
            g2l16(A + (size_t)(o0 + row0 + srow) * C_ + kk + skb * 8,
                  a_s + row0 * 32);
        }
        #pragma unroll
        for (int ib = 0; ib < 2; ++ib) {           // B: 8 instrs, 2/wave
            const int row0 = (wv * 2 + ib) * 16;
            g2l16(xb + (bT0 + row0 + srow) * C_ + kk + skb * 8,
                  b_s + row0 * 32);
        }
        __syncthreads();

        b16x8 af[4], bf[4];
        #pragma unroll
        for (int mi = 0; mi < 4; ++mi) {
            const int m = wm * 64 + mi * 16 + lo;
            af[mi] = *(const b16x8*)(a_s + m * 32 + (quad ^ swz) * 8);
        }
        #pragma unroll
        for (int ni = 0; ni < 4; ++ni) {
            const int n = wn * 64 + ni * 16 + lo;
            bf[ni] = *(const b16x8*)(b_s + n * 32 + (quad ^ swz) * 8);
        }
        #pragma unroll
        for (int mi = 0; mi < 4; ++mi)
            #pragma unroll
            for (int ni = 0; ni < 4; ++ni)
                acc[mi][ni] = __builtin_amdgcn_mfma_f32_16x16x32_bf16(
                    af[mi], bf[ni], acc[mi][ni], 0, 0, 0);
    }

    // C/D layout: col(t)=lane&15, row(o)=quad*4+reg — 4 regs = 4 consecutive o = 4 consecutive dd
    #pragma unroll
    for (int mi = 0; mi < 4; ++mi) {
        const int o_b = o0 + wm * 64 + mi * 16 + quad * 4;
        const float4 bv4 = *(const float4*)(bias + o_b);
        const int h = o_b >> 6;
        const int dd0 = o_b & 63;
        #pragma unroll
        for (int ni = 0; ni < 4; ++ni) {
            const int t = t0 + wn * 64 + ni * 16 + lo;
            f32x4 a = acc[mi][ni];
            ushort4 st;
            st.x = f2b((a[0] + bv4.x) * scale);
            st.y = f2b((a[1] + bv4.y) * scale);
            st.z = f2b((a[2] + bv4.z) * scale);
            st.w = f2b((a[3] + bv4.w) * scale);
            *(ushort4*)(dst + (((size_t)b * H_ + h) * T_ + t) * D_ + dd0) = st;
        }
    }
}

// ---------------------------------------------------------------------------
// Output projection, MFMA bf16. Tile 64(o) x 128(t), 4 waves (2x2), each 32x64.
// A = wob bf16 (o,c), B = ab bf16 (B,T,C). Epilogue fp32 (B,C,T) + bias.
// ---------------------------------------------------------------------------
__global__ __launch_bounds__(256) void out_mfma_kernel(
    const u16* __restrict__ wob, const u16* __restrict__ ab,
    const float* __restrict__ bias, float* __restrict__ out)
{
    __shared__ u16 a_s[64 * 32];
    __shared__ u16 b_s[128 * 32];

    const int tid = threadIdx.x;
    const int wv = tid >> 6, lane = tid & 63;
    const int lo = lane & 15, quad = lane >> 4;
    const int wm = wv >> 1, wn = wv & 1;
    const int swz = (lo >> 1) & 3;
    const int srow = lane >> 2;
    const int skb  = (lane & 3) ^ ((lane >> 3) & 3);

    const int t0 = blockIdx.x * 128;
    const int o0 = blockIdx.y * 64;
    const int b  = blockIdx.z;
    const size_t bT0 = (size_t)b * T_ + t0;

    f32x4 acc[2][4] = {};

    for (int kk = 0; kk < C_; kk += 32) {
        __syncthreads();
        {                                         // A: 4 instrs, 1/wave
            const int row0 = wv * 16;
            g2l16(wob + (size_t)(o0 + row0 + srow) * C_ + kk + skb * 8,
                  a_s + row0 * 32);
        }
        #pragma unroll
        for (int ib = 0; ib < 2; ++ib) {          // B: 8 instrs, 2/wave
            const int row0 = (wv * 2 + ib) * 16;
            g2l16(ab + (bT0 + row0 + srow) * C_ + kk + skb * 8,
                  b_s + row0 * 32);
        }
        __syncthreads();

        b16x8 af[2], bf[4];
        #pragma unroll
        for (int mi = 0; mi < 2; ++mi) {
            const int m = wm * 32 + mi * 16 + lo;
            af[mi] = *(const b16x8*)(a_s + m * 32 + (quad ^ swz) * 8);
        }
        #pragma unroll
        for (int ni = 0; ni < 4; ++ni) {
            const int n = wn * 64 + ni * 16 + lo;
            bf[ni] = *(const b16x8*)(b_s + n * 32 + (quad ^ swz) * 8);
        }
        #pragma unroll
        for (int mi = 0; mi < 2; ++mi)
            #pragma unroll
            for (int ni = 0; ni < 4; ++ni)
                acc[mi][ni] = __builtin_amdgcn_mfma_f32_16x16x32_bf16(
                    af[mi], bf[ni], acc[mi][ni], 0, 0, 0);
    }

    #pragma unroll
    for (int mi = 0; mi < 2; ++mi) {
        const int o_b = o0 + wm * 32 + mi * 16 + quad * 4;
        const float4 bv4 = *(const float4*)(bias + o_b);
        const float bb[4] = {bv4.x, bv4.y, bv4.z, bv4.w};
        #pragma unroll
        for (int ni = 0; ni < 4; ++ni) {
            const int t = t0 + wn * 64 + ni * 16 + lo;
            f32x4 a = acc[mi][ni];
            #pragma unroll
            for (int r = 0; r < 4; ++r)
                out[((size_t)b * C_ + o_b + r) * T_ + t] = a[r] + bb[r];
        }
    }
}

// ---------------------------------------------------------------------------
// Flash attention with windowed relative-position bias (unchanged compute).
// Epilogue now writes bf16 (B,T,C) — the B-operand layout for out_mfma.
// ---------------------------------------------------------------------------
__global__ __launch_bounds__(256) void attn_kernel(
    const u16* __restrict__ qw, const u16* __restrict__ kw, const u16* __restrict__ vw,
    const float* __restrict__ erk, const float* __restrict__ erv,
    u16* __restrict__ att)
{
    __shared__ __align__(16) float q_s[64][64];   // [dd][i]
    __shared__ __align__(16) float k_s[64][68];   // [dd][j]
    __shared__ __align__(16) u16   v_s[64][68];   // [j][dd] raw bf16 bits
    __shared__ __align__(16) float p_s[64][68];   // [j][i]
    __shared__ __align__(16) float erk_s[9][64];
    __shared__ __align__(16) float erv_s[9][64];
    __shared__ float qrel_s[64][9];
    __shared__ float m_s[64], l_s[64];

    const int tid = threadIdx.x;
    const int tx = tid & 15, ty = tid >> 4;
    const int it0 = blockIdx.x * 64;
    const int h = blockIdx.y, b = blockIdx.z;
    const int bh = b * H_ + h;

    const u16* qp = qw + (size_t)bh * T_ * D_;
    const u16* kp = kw + (size_t)bh * T_ * D_;
    const u16* vp = vw + (size_t)bh * T_ * D_;

    if (tid < 64) { m_s[tid] = -1e30f; l_s[tid] = 0.f; }

    const int sr = tid >> 2, sd4 = (tid & 3) * 4;

    {
        const u16* qrow = qp + (size_t)(it0 + sr) * D_;
        #pragma unroll
        for (int rep = 0; rep < 4; ++rep) {
            const int dd = sd4 + rep * 16;
            ushort4 u = *(const ushort4*)(qrow + dd);
            q_s[dd + 0][sr] = b2f(u.x);
            q_s[dd + 1][sr] = b2f(u.y);
            q_s[dd + 2][sr] = b2f(u.z);
            q_s[dd + 3][sr] = b2f(u.w);
        }
    }
    for (int idx = tid; idx < 9 * 64; idx += 256) {
        erk_s[idx >> 6][idx & 63] = erk[idx];
        erv_s[idx >> 6][idx & 63] = erv[idx];
    }
    __syncthreads();

    for (int idx = tid; idx < 9 * 64; idx += 256) {
        const int i = idx & 63, r = idx >> 6;
        float s = 0.f;
        for (int dd = 0; dd < 64; ++dd) s += q_s[dd][i] * erk_s[r][dd];
        qrel_s[i][r] = s;
    }

    float o_acc[4][4] = {};

    for (int jt = 0; jt < T_; jt += 64) {
        __syncthreads();
        {
            const u16* krow = kp + (size_t)(jt + sr) * D_;
            const u16* vrow = vp + (size_t)(jt + sr) * D_;
            #pragma unroll
            for (int rep = 0; rep < 4; ++rep) {
                const int dd = sd4 + rep * 16;
                ushort4 ku = *(const ushort4*)(krow + dd);
                k_s[dd + 0][sr] = b2f(ku.x);
                k_s[dd + 1][sr] = b2f(ku.y);
                k_s[dd + 2][sr] = b2f(ku.z);
                k_s[dd + 3][sr] = b2f(ku.w);
                *(ushort4*)&v_s[sr][dd] = *(const ushort4*)(vrow + dd);
            }
        }
        __syncthreads();

        float s[4][4] = {};
        #pragma unroll 16
        for (int dd = 0; dd < 64; ++dd) {
            const float4 qv = *(const float4*)&q_s[dd][ty * 4];
            const float4 kv = *(const float4*)&k_s[dd][tx * 4];
            const float qa[4] = {qv.x, qv.y, qv.z, qv.w};
            const float kb[4] = {kv.x, kv.y, kv.z, kv.w};
            #pragma unroll
            for (int ii = 0; ii < 4; ++ii)
                #pragma unroll
                for (int jj = 0; jj < 4; ++jj)
                    s[ii][jj] = fmaf(qa[ii], kb[jj], s[ii][jj]);
        }

        const int diag = jt - it0 + 4;
        #pragma unroll
        for (int ii = 0; ii < 4; ++ii) {
            const int il = ty * 4 + ii;
            #pragma unroll
            for (int jj = 0; jj < 4; ++jj) {
                const int r = diag + tx * 4 + jj - il;
                if (r >= 0 && r <= 8) s[ii][jj] += qrel_s[il][r];
            }
        }

        float alpha[4];
        #pragma unroll
        for (int ii = 0; ii < 4; ++ii) {
            float tm = fmaxf(fmaxf(s[ii][0], s[ii][1]), fmaxf(s[ii][2], s[ii][3]));
            #pragma unroll
            for (int mask = 1; mask < 16; mask <<= 1)
                tm = fmaxf(tm, __shfl_xor(tm, mask));
            const int il = ty * 4 + ii;
            const float mo = m_s[il];
            const float nm = fmaxf(mo, tm);
            float rs = 0.f;
            #pragma unroll
            for (int jj = 0; jj < 4; ++jj) {
                s[ii][jj] = __expf(s[ii][jj] - nm);
                rs += s[ii][jj];
            }
            #pragma unroll
            for (int mask = 1; mask < 16; mask <<= 1)
                rs += __shfl_xor(rs, mask);
            alpha[ii] = __expf(mo - nm);
            if (tx == 0) {
                m_s[il] = nm;
                l_s[il] = l_s[il] * alpha[ii] + rs;
            }
        }

        #pragma unroll
        for (int ii = 0; ii < 4; ++ii)
            #pragma unroll
            for (int jj = 0; jj < 4; ++jj)
                p_s[tx * 4 + jj][ty * 4 + ii] = s[ii][jj];

        #pragma unroll
        for (int ii = 0; ii < 4; ++ii)
            #pragma unroll
            for (int jj = 0; jj < 4; ++jj)
                o_acc[ii][jj] *= alpha[ii];

        __syncthreads();

        #pragma unroll 16
        for (int j = 0; j < 64; ++j) {
            const float4 pv = *(const float4*)&p_s[j][ty * 4];
            const ushort4 vu = *(const ushort4*)&v_s[j][tx * 4];
            const float pa[4] = {pv.x, pv.y, pv.z, pv.w};
            const float vb[4] = {b2f(vu.x), b2f(vu.y), b2f(vu.z), b2f(vu.w)};
            #pragma unroll
            for (int ii = 0; ii < 4; ++ii)
                #pragma unroll
                for (int jj = 0; jj < 4; ++jj)
                    o_acc[ii][jj] = fmaf(pa[ii], vb[jj], o_acc[ii][jj]);
        }

        #pragma unroll
        for (int ii = 0; ii < 4; ++ii) {
            const int il = ty * 4 + ii;
            const int gi = it0 + il;
            #pragma unroll
            for (int r = 0; r <= 8; ++r) {
                const int lj = gi + r - 4 - jt;
                if (lj >= 0 && lj < 64) {
                    const float pr = p_s[lj][il];
                    #pragma unroll
                    for (int jj = 0; jj < 4; ++jj)
                        o_acc[ii][jj] = fmaf(pr, erv_s[r][tx * 4 + jj], o_acc[ii][jj]);
                }
            }
        }
    }

    float inv[4];
    #pragma unroll
    for (int ii = 0; ii < 4; ++ii) inv[ii] = 1.f / l_s[ty * 4 + ii];

    // bf16 (B,T,C): row t = it0+ty*4+ii, col c = h*64 + tx*4 + jj
    #pragma unroll
    for (int ii = 0; ii < 4; ++ii) {
        ushort4 st;
        st.x = f2b(o_acc[ii][0] * inv[ii]);
        st.y = f2b(o_acc[ii][1] * inv[ii]);
        st.z = f2b(o_acc[ii][2] * inv[ii]);
        st.w = f2b(o_acc[ii][3] * inv[ii]);
        *(ushort4*)(att + ((size_t)b * T_ + it0 + ty * 4 + ii) * C_ + h * D_ + tx * 4) = st;
    }
}

extern "C" void kernel_launch(void* const* d_in, const int* in_sizes, int n_in,
                              void* d_out, int out_size, void* d_ws, size_t ws_size,
                              hipStream_t stream) {
    const float* x   = (const float*)d_in[0];
    const float* w_q = (const float*)d_in[1];
    const float* b_q = (const float*)d_in[2];
    const float* w_k = (const float*)d_in[3];
    const float* b_k = (const float*)d_in[4];
    const float* w_v = (const float*)d_in[5];
    const float* b_v = (const float*)d_in[6];
    const float* w_o = (const float*)d_in[7];
    const float* b_o = (const float*)d_in[8];
    const float* erk = (const float*)d_in[9];
    const float* erv = (const float*)d_in[10];

    const size_t N = (size_t)B_ * C_ * T_;   // 3,145,728
    u16* q_ws = (u16*)d_ws;                  // bf16 (B,H,T,d)
    u16* k_ws = q_ws + N;
    u16* v_ws = q_ws + 2 * N;
    u16* a_ws = q_ws + 3 * N;                // bf16 (B,T,C) attention out
    u16* xb   = q_ws + 4 * N;                // bf16 (B,T,C) x transposed
    u16* wb   = q_ws + 5 * N;                // bf16 4x(C,C): wq,wk,wv,wo
    float* out = (float*)d_out;

    dim3 blk(256, 1, 1);

    convw_kernel<<<dim3(C_ * C_ / 1024, 4), blk, 0, stream>>>(w_q, w_k, w_v, w_o, wb);
    convx_kernel<<<dim3(T_ / 64, C_ / 64, B_), blk, 0, stream>>>(x, xb);

    qkv_mfma_kernel<<<dim3(T_ / 128, 18, B_), blk, 0, stream>>>(
        wb, xb, b_q, b_k, b_v, q_ws, k_ws, v_ws);

    attn_kernel<<<dim3(T_ / 64, H_, B_), blk, 0, stream>>>(
        q_ws, k_ws, v_ws, erk, erv, a_ws);

    out_mfma_kernel<<<dim3(T_ / 128, C_ / 64, B_), blk, 0, stream>>>(
        wb + 3 * (size_t)C_ * C_, a_ws, b_o, out);
}

// Round 5
// 194.570 us; speedup vs baseline: 3.3618x; 2.0884x over previous
//
#include <hip/hip_runtime.h>

#define B_ 4
#define T_ 1024
#define C_ 768
#define H_ 12
#define D_ 64

typedef unsigned short u16;
typedef __attribute__((ext_vector_type(8))) short b16x8;   // 8 bf16 (4 VGPRs)
typedef __attribute__((ext_vector_type(4))) float f32x4;   // MFMA C/D

#define MFMA(a, b, c) __builtin_amdgcn_mfma_f32_16x16x32_bf16(a, b, c, 0, 0, 0)

__device__ __forceinline__ float b2f(u16 u) {
    return __uint_as_float(((unsigned)u) << 16);
}
__device__ __forceinline__ u16 f2b(float f) {
    unsigned u = __float_as_uint(f);
    u += 0x7fffu + ((u >> 16) & 1u);   // round-to-nearest-even
    return (u16)(u >> 16);
}

// async global->LDS, 16B per lane; LDS dest = wave-uniform base + lane*16
__device__ __forceinline__ void g2l16(const u16* g, u16* l) {
    __builtin_amdgcn_global_load_lds(
        (const __attribute__((address_space(1))) unsigned int*)g,
        (__attribute__((address_space(3))) unsigned int*)l, 16, 0, 0);
}

// ---------------------------------------------------------------------------
// fp32 -> bf16 weight convert (4 matrices concatenated into wb)
// ---------------------------------------------------------------------------
__global__ __launch_bounds__(256) void convw_kernel(
    const float* __restrict__ w0, const float* __restrict__ w1,
    const float* __restrict__ w2, const float* __restrict__ w3,
    u16* __restrict__ o)
{
    const float* src = blockIdx.y == 0 ? w0 : blockIdx.y == 1 ? w1 :
                       blockIdx.y == 2 ? w2 : w3;
    u16* dst = o + (size_t)blockIdx.y * C_ * C_;
    const int i = (blockIdx.x * 256 + threadIdx.x) * 4;
    float4 v = *(const float4*)(src + i);
    ushort4 st = {f2b(v.x), f2b(v.y), f2b(v.z), f2b(v.w)};
    *(ushort4*)(dst + i) = st;
}

// ---------------------------------------------------------------------------
// x (B,C,T) fp32 -> xb (B,T,C) bf16 (transpose through LDS tile)
// ---------------------------------------------------------------------------
__global__ __launch_bounds__(256) void convx_kernel(
    const float* __restrict__ x, u16* __restrict__ xb)
{
    __shared__ u16 tile[64][68];
    const int tid = threadIdx.x;
    const int t0 = blockIdx.x * 64, c0 = blockIdx.y * 64, b = blockIdx.z;
    #pragma unroll
    for (int p = 0; p < 4; ++p) {
        const int cc = p * 16 + (tid >> 4);
        const int t4 = (tid & 15) * 4;
        float4 v = *(const float4*)(x + ((size_t)b * C_ + c0 + cc) * T_ + t0 + t4);
        tile[t4 + 0][cc] = f2b(v.x);
        tile[t4 + 1][cc] = f2b(v.y);
        tile[t4 + 2][cc] = f2b(v.z);
        tile[t4 + 3][cc] = f2b(v.w);
    }
    __syncthreads();
    #pragma unroll
    for (int p = 0; p < 4; ++p) {
        const int tt = p * 16 + (tid >> 4);
        const int c4 = (tid & 15) * 4;
        ushort4 st = *(const ushort4*)&tile[tt][c4];
        *(ushort4*)(xb + ((size_t)b * T_ + t0 + tt) * C_ + c0 + c4) = st;
    }
}

// ---------------------------------------------------------------------------
// Fused QKV projection, MFMA bf16. Tile 128(o) x 128(t).
// Q,K -> bf16 (B,H,T,d); V -> bf16 (B,H,d,T)  [transposed for PV B-operand]
// ---------------------------------------------------------------------------
__global__ __launch_bounds__(256) void qkv_mfma_kernel(
    const u16* __restrict__ wb, const u16* __restrict__ xb,
    const float* __restrict__ b_q, const float* __restrict__ b_k,
    const float* __restrict__ b_v,
    u16* __restrict__ q_ws, u16* __restrict__ k_ws, u16* __restrict__ v_ws)
{
    __shared__ u16 a_s[128 * 32];
    __shared__ u16 b_s[128 * 32];

    const int tid = threadIdx.x;
    const int wv = tid >> 6, lane = tid & 63;
    const int lo = lane & 15, quad = lane >> 4;
    const int wm = wv >> 1, wn = wv & 1;
    const int swz = (lo >> 1) & 3;
    const int srow = lane >> 2;
    const int skb  = (lane & 3) ^ ((lane >> 3) & 3);

    const int t0 = blockIdx.x * 128;
    const int mat = blockIdx.y / 6, oy = blockIdx.y % 6;
    const int o0 = oy * 128;
    const int b  = blockIdx.z;

    const u16* A = wb + (size_t)mat * C_ * C_;
    const float* bias = mat == 0 ? b_q : (mat == 1 ? b_k : b_v);
    u16* dst = mat == 0 ? q_ws : (mat == 1 ? k_ws : v_ws);
    const float scale = mat == 0 ? 0.125f : 1.0f;

    const size_t bT0 = (size_t)b * T_ + t0;

    f32x4 acc[4][4] = {};

    for (int kk = 0; kk < C_; kk += 32) {
        __syncthreads();
        #pragma unroll
        for (int ia = 0; ia < 2; ++ia) {
            const int row0 = (wv * 2 + ia) * 16;
            g2l16(A + (size_t)(o0 + row0 + srow) * C_ + kk + skb * 8,
                  a_s + row0 * 32);
        }
        #pragma unroll
        for (int ib = 0; ib < 2; ++ib) {
            const int row0 = (wv * 2 + ib) * 16;
            g2l16(xb + (bT0 + row0 + srow) * C_ + kk + skb * 8,
                  b_s + row0 * 32);
        }
        __syncthreads();

        b16x8 af[4], bf[4];
        #pragma unroll
        for (int mi = 0; mi < 4; ++mi) {
            const int m = wm * 64 + mi * 16 + lo;
            af[mi] = *(const b16x8*)(a_s + m * 32 + (quad ^ swz) * 8);
        }
        #pragma unroll
        for (int ni = 0; ni < 4; ++ni) {
            const int n = wn * 64 + ni * 16 + lo;
            bf[ni] = *(const b16x8*)(b_s + n * 32 + (quad ^ swz) * 8);
        }
        #pragma unroll
        for (int mi = 0; mi < 4; ++mi)
            #pragma unroll
            for (int ni = 0; ni < 4; ++ni)
                acc[mi][ni] = MFMA(af[mi], bf[ni], acc[mi][ni]);
    }

    #pragma unroll
    for (int mi = 0; mi < 4; ++mi) {
        const int o_b = o0 + wm * 64 + mi * 16 + quad * 4;
        const float4 bv4 = *(const float4*)(bias + o_b);
        const int h = o_b >> 6;
        const int dd0 = o_b & 63;
        #pragma unroll
        for (int ni = 0; ni < 4; ++ni) {
            const int t = t0 + wn * 64 + ni * 16 + lo;
            f32x4 a = acc[mi][ni];
            if (mat == 2) {
                // (B,H,D,T)
                v_ws[(((size_t)b * H_ + h) * D_ + dd0 + 0) * T_ + t] = f2b(a[0] + bv4.x);
                v_ws[(((size_t)b * H_ + h) * D_ + dd0 + 1) * T_ + t] = f2b(a[1] + bv4.y);
                v_ws[(((size_t)b * H_ + h) * D_ + dd0 + 2) * T_ + t] = f2b(a[2] + bv4.z);
                v_ws[(((size_t)b * H_ + h) * D_ + dd0 + 3) * T_ + t] = f2b(a[3] + bv4.w);
            } else {
                ushort4 st;
                st.x = f2b((a[0] + bv4.x) * scale);
                st.y = f2b((a[1] + bv4.y) * scale);
                st.z = f2b((a[2] + bv4.z) * scale);
                st.w = f2b((a[3] + bv4.w) * scale);
                *(ushort4*)(dst + (((size_t)b * H_ + h) * T_ + t) * D_ + dd0) = st;
            }
        }
    }
}

// ---------------------------------------------------------------------------
// Output projection, MFMA bf16 (unchanged from round 4).
// ---------------------------------------------------------------------------
__global__ __launch_bounds__(256) void out_mfma_kernel(
    const u16* __restrict__ wob, const u16* __restrict__ ab,
    const float* __restrict__ bias, float* __restrict__ out)
{
    __shared__ u16 a_s[64 * 32];
    __shared__ u16 b_s[128 * 32];

    const int tid = threadIdx.x;
    const int wv = tid >> 6, lane = tid & 63;
    const int lo = lane & 15, quad = lane >> 4;
    const int wm = wv >> 1, wn = wv & 1;
    const int swz = (lo >> 1) & 3;
    const int srow = lane >> 2;
    const int skb  = (lane & 3) ^ ((lane >> 3) & 3);

    const int t0 = blockIdx.x * 128;
    const int o0 = blockIdx.y * 64;
    const int b  = blockIdx.z;
    const size_t bT0 = (size_t)b * T_ + t0;

    f32x4 acc[2][4] = {};

    for (int kk = 0; kk < C_; kk += 32) {
        __syncthreads();
        {
            const int row0 = wv * 16;
            g2l16(wob + (size_t)(o0 + row0 + srow) * C_ + kk + skb * 8,
                  a_s + row0 * 32);
        }
        #pragma unroll
        for (int ib = 0; ib < 2; ++ib) {
            const int row0 = (wv * 2 + ib) * 16;
            g2l16(ab + (bT0 + row0 + srow) * C_ + kk + skb * 8,
                  b_s + row0 * 32);
        }
        __syncthreads();

        b16x8 af[2], bf[4];
        #pragma unroll
        for (int mi = 0; mi < 2; ++mi) {
            const int m = wm * 32 + mi * 16 + lo;
            af[mi] = *(const b16x8*)(a_s + m * 32 + (quad ^ swz) * 8);
        }
        #pragma unroll
        for (int ni = 0; ni < 4; ++ni) {
            const int n = wn * 64 + ni * 16 + lo;
            bf[ni] = *(const b16x8*)(b_s + n * 32 + (quad ^ swz) * 8);
        }
        #pragma unroll
        for (int mi = 0; mi < 2; ++mi)
            #pragma unroll
            for (int ni = 0; ni < 4; ++ni)
                acc[mi][ni] = MFMA(af[mi], bf[ni], acc[mi][ni]);
    }

    #pragma unroll
    for (int mi = 0; mi < 2; ++mi) {
        const int o_b = o0 + wm * 32 + mi * 16 + quad * 4;
        const float4 bv4 = *(const float4*)(bias + o_b);
        const float bb[4] = {bv4.x, bv4.y, bv4.z, bv4.w};
        #pragma unroll
        for (int ni = 0; ni < 4; ++ni) {
            const int t = t0 + wn * 64 + ni * 16 + lo;
            f32x4 a = acc[mi][ni];
            #pragma unroll
            for (int r = 0; r < 4; ++r)
                out[((size_t)b * C_ + o_b + r) * T_ + t] = a[r] + bb[r];
        }
    }
}

// ---------------------------------------------------------------------------
// MFMA flash attention with windowed relative bias.
// Block = (b, h, 128 query rows); 4 waves x 32 rows.
// q,k: (B,H,T,d) bf16; v: (B,H,d,T) bf16. Out: bf16 (B,T,C).
// S^T = K·Q^T (A=K m=j, B=Q n=i) -> softmax (2 shuffles) -> P via LDS
// (wave-local) -> O = P·V (A=P m=i, B=V n=dd).
// rel-k: qrel = Q·erk^T via MFMA prologue; rel-v: band-logit capture +
// one MFMA epilogue exp(band - m_fin)·erv.
// ---------------------------------------------------------------------------
__global__ __launch_bounds__(256, 2) void attn_mfma_kernel(
    const u16* __restrict__ qw, const u16* __restrict__ kw, const u16* __restrict__ vw,
    const float* __restrict__ erk, const float* __restrict__ erv,
    u16* __restrict__ att)
{
    __shared__ u16 k_s[64 * 72];       // [j][d], stride 72
    __shared__ u16 v_s[64 * 72];       // [dd][j], stride 72
    __shared__ u16 p_s[128 * 72];      // [i][j], stride 72
    __shared__ float qrel_s[128][9];
    __shared__ float band_s[128][9];
    __shared__ float alpha_s[128];

    const int tid = threadIdx.x;
    const int wv = tid >> 6, lane = tid & 63;
    const int lo = lane & 15, quad = lane >> 4;
    const int wi0 = wv * 32;
    const int it0 = blockIdx.x * 128;
    const int h = blockIdx.y, b = blockIdx.z;
    const int bh = b * H_ + h;

    const u16* qp = qw + (size_t)bh * T_ * D_;
    const u16* kp = kw + (size_t)bh * T_ * D_;
    const u16* vp = vw + (size_t)bh * D_ * T_;

    // Q B-frags (n=i, k=d) — registers for the whole kernel
    b16x8 qf[2][2];
    #pragma unroll
    for (int nt = 0; nt < 2; ++nt)
        #pragma unroll
        for (int kc = 0; kc < 2; ++kc)
            qf[nt][kc] = *(const b16x8*)(
                qp + (size_t)(it0 + wi0 + nt * 16 + lo) * D_ + kc * 32 + quad * 8);

    // qrel[i][r] = q_i . erk_r  via MFMA (A=Q frags reused, B=erk)
    {
        b16x8 ekf[2];
        #pragma unroll
        for (int kc = 0; kc < 2; ++kc) {
            union { b16x8 v; u16 s[8]; } t;
            #pragma unroll
            for (int r = 0; r < 8; ++r) t.s[r] = 0;
            if (lo < 9) {
                const float* e = erk + lo * D_ + kc * 32 + quad * 8;
                #pragma unroll
                for (int r = 0; r < 8; ++r) t.s[r] = f2b(e[r]);
            }
            ekf[kc] = t.v;
        }
        #pragma unroll
        for (int it = 0; it < 2; ++it) {
            f32x4 acc = {};
            acc = MFMA(qf[it][0], ekf[0], acc);
            acc = MFMA(qf[it][1], ekf[1], acc);
            if (lo < 9)
                #pragma unroll
                for (int r = 0; r < 4; ++r)
                    qrel_s[wi0 + it * 16 + quad * 4 + r][lo] = acc[r];
        }
    }

    for (int idx = tid; idx < 128 * 9; idx += 256)
        (&band_s[0][0])[idx] = -1e30f;

    f32x4 o[2][4] = {};
    float mstate[2] = {-1e30f, -1e30f};
    float lstate[2] = {0.f, 0.f};

    for (int jt = 0; jt < T_; jt += 64) {
        __syncthreads();                       // prev-tile readers done (also covers init)
        #pragma unroll
        for (int rnd = 0; rnd < 2; ++rnd) {
            const int c0 = tid + rnd * 256;
            const int row = c0 >> 3, ch = c0 & 7;
            *(b16x8*)(k_s + row * 72 + ch * 8) =
                *(const b16x8*)(kp + (size_t)(jt + row) * D_ + ch * 8);
            *(b16x8*)(v_s + row * 72 + ch * 8) =
                *(const b16x8*)(vp + (size_t)row * T_ + jt + ch * 8);
        }
        __syncthreads();

        // S^T tile: m=j (4 tiles), n=i (2 tiles)
        f32x4 st[4][2];
        #pragma unroll
        for (int mt = 0; mt < 4; ++mt) {
            const b16x8 ka0 = *(const b16x8*)(k_s + (mt * 16 + lo) * 72 + quad * 8);
            const b16x8 ka1 = *(const b16x8*)(k_s + (mt * 16 + lo) * 72 + 32 + quad * 8);
            #pragma unroll
            for (int nt = 0; nt < 2; ++nt) {
                f32x4 a = {};
                a = MFMA(ka0, qf[nt][0], a);
                a = MFMA(ka1, qf[nt][1], a);
                st[mt][nt] = a;
            }
        }

        // windowed rel-k bias + band-logit capture
        #pragma unroll
        for (int mt = 0; mt < 4; ++mt)
            #pragma unroll
            for (int nt = 0; nt < 2; ++nt)
                #pragma unroll
                for (int r = 0; r < 4; ++r) {
                    const int il = wi0 + nt * 16 + lo;
                    const int rr = (jt + mt * 16 + quad * 4 + r) - (it0 + il) + 4;
                    if (rr >= 0 && rr <= 8) {
                        const float s2 = st[mt][nt][r] + qrel_s[il][rr];
                        st[mt][nt][r] = s2;
                        band_s[il][rr] = s2;
                    }
                }

        // online softmax per i-tile (reduce over quads: masks 16, 32)
        #pragma unroll
        for (int nt = 0; nt < 2; ++nt) {
            float tm = -1e30f;
            #pragma unroll
            for (int mt = 0; mt < 4; ++mt)
                #pragma unroll
                for (int r = 0; r < 4; ++r)
                    tm = fmaxf(tm, st[mt][nt][r]);
            tm = fmaxf(tm, __shfl_xor(tm, 16));
            tm = fmaxf(tm, __shfl_xor(tm, 32));
            const float nm = fmaxf(mstate[nt], tm);
            const float al = __expf(mstate[nt] - nm);
            mstate[nt] = nm;
            float rs = 0.f;
            #pragma unroll
            for (int mt = 0; mt < 4; ++mt)
                #pragma unroll
                for (int r = 0; r < 4; ++r) {
                    const float e = __expf(st[mt][nt][r] - nm);
                    st[mt][nt][r] = e;
                    rs += e;
                }
            rs += __shfl_xor(rs, 16);
            rs += __shfl_xor(rs, 32);
            lstate[nt] = lstate[nt] * al + rs;
            if (quad == 0) alpha_s[wi0 + nt * 16 + lo] = al;
        }

        // P -> LDS (wave-local rows), bf16 packed
        #pragma unroll
        for (int nt = 0; nt < 2; ++nt) {
            const int il = wi0 + nt * 16 + lo;
            #pragma unroll
            for (int mt = 0; mt < 4; ++mt) {
                ushort4 pw;
                pw.x = f2b(st[mt][nt][0]);
                pw.y = f2b(st[mt][nt][1]);
                pw.z = f2b(st[mt][nt][2]);
                pw.w = f2b(st[mt][nt][3]);
                *(ushort4*)(p_s + il * 72 + mt * 16 + quad * 4) = pw;
            }
        }

        // rescale O by alpha (per O-layout row)
        #pragma unroll
        for (int it = 0; it < 2; ++it)
            #pragma unroll
            for (int r = 0; r < 4; ++r) {
                const float a = alpha_s[wi0 + it * 16 + quad * 4 + r];
                #pragma unroll
                for (int nd = 0; nd < 4; ++nd)
                    o[it][nd][r] *= a;
            }

        // O += P·V
        b16x8 vb[4][2];
        #pragma unroll
        for (int nd = 0; nd < 4; ++nd) {
            vb[nd][0] = *(const b16x8*)(v_s + (nd * 16 + lo) * 72 + quad * 8);
            vb[nd][1] = *(const b16x8*)(v_s + (nd * 16 + lo) * 72 + 32 + quad * 8);
        }
        #pragma unroll
        for (int it = 0; it < 2; ++it) {
            const b16x8 pa0 = *(const b16x8*)(p_s + (wi0 + it * 16 + lo) * 72 + quad * 8);
            const b16x8 pa1 = *(const b16x8*)(p_s + (wi0 + it * 16 + lo) * 72 + 32 + quad * 8);
            #pragma unroll
            for (int nd = 0; nd < 4; ++nd) {
                o[it][nd] = MFMA(pa0, vb[nd][0], o[it][nd]);
                o[it][nd] = MFMA(pa1, vb[nd][1], o[it][nd]);
            }
        }
    }

    // rel-v: O += exp(band - m_fin) · erv  (single k=32 MFMA per tile pair)
    b16x8 baf[2];
    #pragma unroll
    for (int it = 0; it < 2; ++it) {
        const int il = wi0 + it * 16 + lo;
        union { b16x8 v; u16 s[8]; } t;
        #pragma unroll
        for (int r = 0; r < 8; ++r) {
            const int rr = quad * 8 + r;
            const float e = (rr <= 8) ? __expf(band_s[il][rr] - mstate[it]) : 0.f;
            t.s[r] = f2b(e);
        }
        baf[it] = t.v;
    }
    #pragma unroll
    for (int nd = 0; nd < 4; ++nd) {
        union { b16x8 v; u16 s[8]; } t;
        #pragma unroll
        for (int r = 0; r < 8; ++r) {
            const int rr = quad * 8 + r;
            t.s[r] = (rr <= 8) ? f2b(erv[rr * D_ + nd * 16 + lo]) : (u16)0;
        }
        #pragma unroll
        for (int it = 0; it < 2; ++it)
            o[it][nd] = MFMA(baf[it], t.v, o[it][nd]);
    }

    // normalize + store bf16 (B,T,C)
    #pragma unroll
    for (int nt = 0; nt < 2; ++nt)
        if (quad == 0) alpha_s[wi0 + nt * 16 + lo] = 1.f / lstate[nt];

    #pragma unroll
    for (int it = 0; it < 2; ++it)
        #pragma unroll
        for (int r = 0; r < 4; ++r) {
            const int il = wi0 + it * 16 + quad * 4 + r;
            const float li = alpha_s[il];
            const size_t base = ((size_t)b * T_ + it0 + il) * C_ + h * D_;
            #pragma unroll
            for (int nd = 0; nd < 4; ++nd)
                att[base + nd * 16 + lo] = f2b(o[it][nd][r] * li);
        }
}

extern "C" void kernel_launch(void* const* d_in, const int* in_sizes, int n_in,
                              void* d_out, int out_size, void* d_ws, size_t ws_size,
                              hipStream_t stream) {
    const float* x   = (const float*)d_in[0];
    const float* w_q = (const float*)d_in[1];
    const float* b_q = (const float*)d_in[2];
    const float* w_k = (const float*)d_in[3];
    const float* b_k = (const float*)d_in[4];
    const float* w_v = (const float*)d_in[5];
    const float* b_v = (const float*)d_in[6];
    const float* w_o = (const float*)d_in[7];
    const float* b_o = (const float*)d_in[8];
    const float* erk = (const float*)d_in[9];
    const float* erv = (const float*)d_in[10];

    const size_t N = (size_t)B_ * C_ * T_;   // 3,145,728
    u16* q_ws = (u16*)d_ws;                  // bf16 (B,H,T,d)
    u16* k_ws = q_ws + N;                    // bf16 (B,H,T,d)
    u16* v_ws = q_ws + 2 * N;                // bf16 (B,H,d,T)  [transposed]
    u16* a_ws = q_ws + 3 * N;                // bf16 (B,T,C) attention out
    u16* xb   = q_ws + 4 * N;                // bf16 (B,T,C) x transposed
    u16* wb   = q_ws + 5 * N;                // bf16 4x(C,C): wq,wk,wv,wo
    float* out = (float*)d_out;

    dim3 blk(256, 1, 1);

    convw_kernel<<<dim3(C_ * C_ / 1024, 4), blk, 0, stream>>>(w_q, w_k, w_v, w_o, wb);
    convx_kernel<<<dim3(T_ / 64, C_ / 64, B_), blk, 0, stream>>>(x, xb);

    qkv_mfma_kernel<<<dim3(T_ / 128, 18, B_), blk, 0, stream>>>(
        wb, xb, b_q, b_k, b_v, q_ws, k_ws, v_ws);

    attn_mfma_kernel<<<dim3(T_ / 128, H_, B_), blk, 0, stream>>>(
        q_ws, k_ws, v_ws, erk, erv, a_ws);

    out_mfma_kernel<<<dim3(T_ / 128, C_ / 64, B_), blk, 0, stream>>>(
        wb + 3 * (size_t)C_ * C_, a_ws, b_o, out);
}

// Round 6
// 174.555 us; speedup vs baseline: 3.7473x; 1.1147x over previous
//
#include <hip/hip_runtime.h>

#define B_ 4
#define T_ 1024
#define C_ 768
#define H_ 12
#define D_ 64

typedef unsigned short u16;
typedef __attribute__((ext_vector_type(8))) short b16x8;   // 8 bf16 (4 VGPRs)
typedef __attribute__((ext_vector_type(4))) float f32x4;   // MFMA C/D

#define MFMA(a, b, c) __builtin_amdgcn_mfma_f32_16x16x32_bf16(a, b, c, 0, 0, 0)

__device__ __forceinline__ float b2f(u16 u) {
    return __uint_as_float(((unsigned)u) << 16);
}
__device__ __forceinline__ u16 f2b(float f) {
    unsigned u = __float_as_uint(f);
    u += 0x7fffu + ((u >> 16) & 1u);   // round-to-nearest-even
    return (u16)(u >> 16);
}
__device__ __forceinline__ u16 f2b_tr(float f) {    // truncate (cheap, P in [0,1])
    return (u16)(__float_as_uint(f) >> 16);
}

// async global->LDS, 16B per lane; LDS dest = wave-uniform base + lane*16
__device__ __forceinline__ void g2l16(const u16* g, u16* l) {
    __builtin_amdgcn_global_load_lds(
        (const __attribute__((address_space(1))) unsigned int*)g,
        (__attribute__((address_space(3))) unsigned int*)l, 16, 0, 0);
}

// ---------------------------------------------------------------------------
// fp32 -> bf16 weight convert (4 matrices concatenated into wb)
// ---------------------------------------------------------------------------
__global__ __launch_bounds__(256) void convw_kernel(
    const float* __restrict__ w0, const float* __restrict__ w1,
    const float* __restrict__ w2, const float* __restrict__ w3,
    u16* __restrict__ o)
{
    const float* src = blockIdx.y == 0 ? w0 : blockIdx.y == 1 ? w1 :
                       blockIdx.y == 2 ? w2 : w3;
    u16* dst = o + (size_t)blockIdx.y * C_ * C_;
    const int i = (blockIdx.x * 256 + threadIdx.x) * 4;
    float4 v = *(const float4*)(src + i);
    ushort4 st = {f2b(v.x), f2b(v.y), f2b(v.z), f2b(v.w)};
    *(ushort4*)(dst + i) = st;
}

// ---------------------------------------------------------------------------
// x (B,C,T) fp32 -> xb (B,T,C) bf16 (transpose through LDS tile)
// ---------------------------------------------------------------------------
__global__ __launch_bounds__(256) void convx_kernel(
    const float* __restrict__ x, u16* __restrict__ xb)
{
    __shared__ u16 tile[64][68];
    const int tid = threadIdx.x;
    const int t0 = blockIdx.x * 64, c0 = blockIdx.y * 64, b = blockIdx.z;
    #pragma unroll
    for (int p = 0; p < 4; ++p) {
        const int cc = p * 16 + (tid >> 4);
        const int t4 = (tid & 15) * 4;
        float4 v = *(const float4*)(x + ((size_t)b * C_ + c0 + cc) * T_ + t0 + t4);
        tile[t4 + 0][cc] = f2b(v.x);
        tile[t4 + 1][cc] = f2b(v.y);
        tile[t4 + 2][cc] = f2b(v.z);
        tile[t4 + 3][cc] = f2b(v.w);
    }
    __syncthreads();
    #pragma unroll
    for (int p = 0; p < 4; ++p) {
        const int tt = p * 16 + (tid >> 4);
        const int c4 = (tid & 15) * 4;
        ushort4 st = *(const ushort4*)&tile[tt][c4];
        *(ushort4*)(xb + ((size_t)b * T_ + t0 + tt) * C_ + c0 + c4) = st;
    }
}

// ---------------------------------------------------------------------------
// Fused QKV projection, MFMA bf16. Tile 128(o) x 128(t).
// All three mats -> bf16 (B,H,T,d) with coalesced ushort4 stores (V gets
// transposed to (B,H,D,T) by transv_kernel afterwards).
// ---------------------------------------------------------------------------
__global__ __launch_bounds__(256) void qkv_mfma_kernel(
    const u16* __restrict__ wb, const u16* __restrict__ xb,
    const float* __restrict__ b_q, const float* __restrict__ b_k,
    const float* __restrict__ b_v,
    u16* __restrict__ q_ws, u16* __restrict__ k_ws, u16* __restrict__ v_ws)
{
    __shared__ __align__(16) u16 a_s[128 * 32];
    __shared__ __align__(16) u16 b_s[128 * 32];

    const int tid = threadIdx.x;
    const int wv = tid >> 6, lane = tid & 63;
    const int lo = lane & 15, quad = lane >> 4;
    const int wm = wv >> 1, wn = wv & 1;
    const int swz = (lo >> 1) & 3;
    const int srow = lane >> 2;
    const int skb  = (lane & 3) ^ ((lane >> 3) & 3);

    const int t0 = blockIdx.x * 128;
    const int mat = blockIdx.y / 6, oy = blockIdx.y % 6;
    const int o0 = oy * 128;
    const int b  = blockIdx.z;

    const u16* A = wb + (size_t)mat * C_ * C_;
    const float* bias = mat == 0 ? b_q : (mat == 1 ? b_k : b_v);
    u16* dst = mat == 0 ? q_ws : (mat == 1 ? k_ws : v_ws);
    const float scale = mat == 0 ? 0.125f : 1.0f;

    const size_t bT0 = (size_t)b * T_ + t0;

    f32x4 acc[4][4] = {};

    for (int kk = 0; kk < C_; kk += 32) {
        __syncthreads();
        #pragma unroll
        for (int ia = 0; ia < 2; ++ia) {
            const int row0 = (wv * 2 + ia) * 16;
            g2l16(A + (size_t)(o0 + row0 + srow) * C_ + kk + skb * 8,
                  a_s + row0 * 32);
        }
        #pragma unroll
        for (int ib = 0; ib < 2; ++ib) {
            const int row0 = (wv * 2 + ib) * 16;
            g2l16(xb + (bT0 + row0 + srow) * C_ + kk + skb * 8,
                  b_s + row0 * 32);
        }
        __syncthreads();

        b16x8 af[4], bf[4];
        #pragma unroll
        for (int mi = 0; mi < 4; ++mi) {
            const int m = wm * 64 + mi * 16 + lo;
            af[mi] = *(const b16x8*)(a_s + m * 32 + (quad ^ swz) * 8);
        }
        #pragma unroll
        for (int ni = 0; ni < 4; ++ni) {
            const int n = wn * 64 + ni * 16 + lo;
            bf[ni] = *(const b16x8*)(b_s + n * 32 + (quad ^ swz) * 8);
        }
        #pragma unroll
        for (int mi = 0; mi < 4; ++mi)
            #pragma unroll
            for (int ni = 0; ni < 4; ++ni)
                acc[mi][ni] = MFMA(af[mi], bf[ni], acc[mi][ni]);
    }

    #pragma unroll
    for (int mi = 0; mi < 4; ++mi) {
        const int o_b = o0 + wm * 64 + mi * 16 + quad * 4;
        const float4 bv4 = *(const float4*)(bias + o_b);
        const int h = o_b >> 6;
        const int dd0 = o_b & 63;
        #pragma unroll
        for (int ni = 0; ni < 4; ++ni) {
            const int t = t0 + wn * 64 + ni * 16 + lo;
            f32x4 a = acc[mi][ni];
            ushort4 st;
            st.x = f2b((a[0] + bv4.x) * scale);
            st.y = f2b((a[1] + bv4.y) * scale);
            st.z = f2b((a[2] + bv4.z) * scale);
            st.w = f2b((a[3] + bv4.w) * scale);
            *(ushort4*)(dst + (((size_t)b * H_ + h) * T_ + t) * D_ + dd0) = st;
        }
    }
}

// ---------------------------------------------------------------------------
// v (B,H,T,d) bf16 -> (B,H,D,T) bf16 (transpose through LDS tile)
// ---------------------------------------------------------------------------
__global__ __launch_bounds__(256) void transv_kernel(
    const u16* __restrict__ src, u16* __restrict__ dst)
{
    __shared__ __align__(16) u16 tile[64 * 72];
    const int tid = threadIdx.x;
    const int t0 = blockIdx.x * 64;
    const int bh = blockIdx.y;
    const u16* s = src + (size_t)bh * T_ * D_;
    u16* d = dst + (size_t)bh * D_ * T_;
    #pragma unroll
    for (int p = 0; p < 2; ++p) {
        const int idx = tid + p * 256;
        const int row = idx >> 3, ch = idx & 7;
        *(b16x8*)(tile + row * 72 + ch * 8) =
            *(const b16x8*)(s + (size_t)(t0 + row) * D_ + ch * 8);
    }
    __syncthreads();
    #pragma unroll
    for (int p = 0; p < 2; ++p) {
        const int idx = tid + p * 256;
        const int dd = idx >> 3, ch = idx & 7;
        union { b16x8 v; u16 e[8]; } t;
        #pragma unroll
        for (int e = 0; e < 8; ++e)
            t.e[e] = tile[(ch * 8 + e) * 72 + dd];
        *(b16x8*)(d + (size_t)dd * T_ + t0 + ch * 8) = t.v;
    }
}

// ---------------------------------------------------------------------------
// Output projection, MFMA bf16.
// ---------------------------------------------------------------------------
__global__ __launch_bounds__(256) void out_mfma_kernel(
    const u16* __restrict__ wob, const u16* __restrict__ ab,
    const float* __restrict__ bias, float* __restrict__ out)
{
    __shared__ __align__(16) u16 a_s[64 * 32];
    __shared__ __align__(16) u16 b_s[128 * 32];

    const int tid = threadIdx.x;
    const int wv = tid >> 6, lane = tid & 63;
    const int lo = lane & 15, quad = lane >> 4;
    const int wm = wv >> 1, wn = wv & 1;
    const int swz = (lo >> 1) & 3;
    const int srow = lane >> 2;
    const int skb  = (lane & 3) ^ ((lane >> 3) & 3);

    const int t0 = blockIdx.x * 128;
    const int o0 = blockIdx.y * 64;
    const int b  = blockIdx.z;
    const size_t bT0 = (size_t)b * T_ + t0;

    f32x4 acc[2][4] = {};

    for (int kk = 0; kk < C_; kk += 32) {
        __syncthreads();
        {
            const int row0 = wv * 16;
            g2l16(wob + (size_t)(o0 + row0 + srow) * C_ + kk + skb * 8,
                  a_s + row0 * 32);
        }
        #pragma unroll
        for (int ib = 0; ib < 2; ++ib) {
            const int row0 = (wv * 2 + ib) * 16;
            g2l16(ab + (bT0 + row0 + srow) * C_ + kk + skb * 8,
                  b_s + row0 * 32);
        }
        __syncthreads();

        b16x8 af[2], bf[4];
        #pragma unroll
        for (int mi = 0; mi < 2; ++mi) {
            const int m = wm * 32 + mi * 16 + lo;
            af[mi] = *(const b16x8*)(a_s + m * 32 + (quad ^ swz) * 8);
        }
        #pragma unroll
        for (int ni = 0; ni < 4; ++ni) {
            const int n = wn * 64 + ni * 16 + lo;
            bf[ni] = *(const b16x8*)(b_s + n * 32 + (quad ^ swz) * 8);
        }
        #pragma unroll
        for (int mi = 0; mi < 2; ++mi)
            #pragma unroll
            for (int ni = 0; ni < 4; ++ni)
                acc[mi][ni] = MFMA(af[mi], bf[ni], acc[mi][ni]);
    }

    #pragma unroll
    for (int mi = 0; mi < 2; ++mi) {
        const int o_b = o0 + wm * 32 + mi * 16 + quad * 4;
        const float4 bv4 = *(const float4*)(bias + o_b);
        const float bb[4] = {bv4.x, bv4.y, bv4.z, bv4.w};
        #pragma unroll
        for (int ni = 0; ni < 4; ++ni) {
            const int t = t0 + wn * 64 + ni * 16 + lo;
            f32x4 a = acc[mi][ni];
            #pragma unroll
            for (int r = 0; r < 4; ++r)
                out[((size_t)b * C_ + o_b + r) * T_ + t] = a[r] + bb[r];
        }
    }
}

// ---------------------------------------------------------------------------
// MFMA flash attention, 64-row Q blocks (4 waves x 16 rows), grid 16x12x4.
// q,k: (B,H,T,d) bf16; v: (B,H,D,T) bf16. Out: bf16 (B,T,C).
// K/V staged via global_load_lds with XOR chunk swizzle (stride 64, no pad).
// S^T = K.Q^T -> online softmax (2 shuffles) -> P in LDS (swizzled, wave-
// local) -> O += P.V. rel-k via MFMA prologue; rel-v via band capture +
// MFMA epilogue. No barriers besides the 2 staging barriers per tile.
// ---------------------------------------------------------------------------
__global__ __launch_bounds__(256, 2) void attn_mfma_kernel(
    const u16* __restrict__ qw, const u16* __restrict__ kw, const u16* __restrict__ vw,
    const float* __restrict__ erk, const float* __restrict__ erv,
    u16* __restrict__ att)
{
    __shared__ __align__(16) u16 k_s[64 * 64];   // [j][d], 16B chunks XOR-swizzled
    __shared__ __align__(16) u16 v_s[64 * 64];   // [dd][j], swizzled
    __shared__ __align__(16) u16 p_s[64 * 64];   // [i][j], swizzled
    __shared__ float qrel_s[64][9];
    __shared__ float band_s[64][9];
    __shared__ float alpha_s[64];

    const int tid = threadIdx.x;
    const int wv = tid >> 6, lane = tid & 63;
    const int lo = lane & 15, quad = lane >> 4;
    const int wi0 = wv * 16;
    const int it0 = blockIdx.x * 64;
    const int h = blockIdx.y, b = blockIdx.z;
    const int bh = b * H_ + h;

    const u16* qp = qw + (size_t)bh * T_ * D_;
    const u16* kp = kw + (size_t)bh * T_ * D_;
    const u16* vp = vw + (size_t)bh * D_ * T_;

    const int srow = lane >> 3;                    // row within 8-row instr group
    const int schunk = (lane & 7) ^ (srow & 7);    // swizzled source chunk
    const int lsw = lo & 7;                        // read-side swizzle key

    // Q frags (A/B layouts coincide): row i = it0+wi0+lo, k = kc*32+quad*8
    b16x8 qf[2];
    #pragma unroll
    for (int kc = 0; kc < 2; ++kc)
        qf[kc] = *(const b16x8*)(qp + (size_t)(it0 + wi0 + lo) * D_ + kc * 32 + quad * 8);

    // qrel[i][r] = q_i . erk_r via MFMA (A=Q, B=erk)
    {
        b16x8 ekf[2];
        #pragma unroll
        for (int kc = 0; kc < 2; ++kc) {
            union { b16x8 v; u16 s[8]; } t;
            #pragma unroll
            for (int r = 0; r < 8; ++r) t.s[r] = 0;
            if (lo < 9) {
                const float* e = erk + lo * D_ + kc * 32 + quad * 8;
                #pragma unroll
                for (int r = 0; r < 8; ++r) t.s[r] = f2b(e[r]);
            }
            ekf[kc] = t.v;
        }
        f32x4 acc = {};
        acc = MFMA(qf[0], ekf[0], acc);
        acc = MFMA(qf[1], ekf[1], acc);
        if (lo < 9)
            #pragma unroll
            for (int r = 0; r < 4; ++r)
                qrel_s[wi0 + quad * 4 + r][lo] = acc[r];
    }

    // band init (wave-local rows only -> no barrier needed)
    for (int idx = lane; idx < 16 * 9; idx += 64)
        band_s[wi0 + idx / 9][idx % 9] = -1e30f;

    f32x4 o[4] = {};
    float m = -1e30f, l = 0.f;

    for (int jt = 0; jt < T_; jt += 64) {
        __syncthreads();
        #pragma unroll
        for (int i2 = 0; i2 < 2; ++i2) {
            const int row0 = (wv * 2 + i2) * 8;
            g2l16(kp + (size_t)(jt + row0 + srow) * D_ + schunk * 8, k_s + row0 * 64);
            g2l16(vp + (size_t)(row0 + srow) * T_ + jt + schunk * 8, v_s + row0 * 64);
        }
        __syncthreads();

        // S^T: A=K (m=j), B=Q (n=i)
        f32x4 st[4];
        #pragma unroll
        for (int mt = 0; mt < 4; ++mt) {
            const int kr = mt * 16 + lo;
            const b16x8 ka0 = *(const b16x8*)(k_s + kr * 64 + ((quad) ^ lsw) * 8);
            const b16x8 ka1 = *(const b16x8*)(k_s + kr * 64 + ((4 + quad) ^ lsw) * 8);
            f32x4 a = {};
            a = MFMA(ka0, qf[0], a);
            a = MFMA(ka1, qf[1], a);
            st[mt] = a;
        }

        // windowed rel-k bias + band-logit capture (i = it0+wi0+lo, j = row)
        const int ibase = it0 + wi0 + lo;
        #pragma unroll
        for (int mt = 0; mt < 4; ++mt)
            #pragma unroll
            for (int r = 0; r < 4; ++r) {
                const int rr = (jt + mt * 16 + quad * 4 + r) - ibase + 4;
                if (rr >= 0 && rr <= 8) {
                    const float s2 = st[mt][r] + qrel_s[wi0 + lo][rr];
                    st[mt][r] = s2;
                    band_s[wi0 + lo][rr] = s2;
                }
            }

        // online softmax per column i (reduce across quads)
        float tm = -1e30f;
        #pragma unroll
        for (int mt = 0; mt < 4; ++mt)
            #pragma unroll
            for (int r = 0; r < 4; ++r)
                tm = fmaxf(tm, st[mt][r]);
        tm = fmaxf(tm, __shfl_xor(tm, 16));
        tm = fmaxf(tm, __shfl_xor(tm, 32));
        const float nm = fmaxf(m, tm);
        const float al = __expf(m - nm);
        m = nm;
        float rs = 0.f;
        #pragma unroll
        for (int mt = 0; mt < 4; ++mt)
            #pragma unroll
            for (int r = 0; r < 4; ++r) {
                const float e = __expf(st[mt][r] - nm);
                st[mt][r] = e;
                rs += e;
            }
        rs += __shfl_xor(rs, 16);
        rs += __shfl_xor(rs, 32);
        l = l * al + rs;
        if (quad == 0) alpha_s[wi0 + lo] = al;

        // P -> LDS (wave-local rows), truncating pack, swizzled chunks
        #pragma unroll
        for (int mt = 0; mt < 4; ++mt) {
            ushort4 pw;
            pw.x = f2b_tr(st[mt][0]);
            pw.y = f2b_tr(st[mt][1]);
            pw.z = f2b_tr(st[mt][2]);
            pw.w = f2b_tr(st[mt][3]);
            const int slot = (mt * 2 + (quad >> 1)) ^ lsw;
            *(ushort4*)(p_s + (wi0 + lo) * 64 + slot * 8 + (quad & 1) * 4) = pw;
        }

        // rescale O rows (row i = wi0 + quad*4 + r)
        #pragma unroll
        for (int r = 0; r < 4; ++r) {
            const float a = alpha_s[wi0 + quad * 4 + r];
            #pragma unroll
            for (int nd = 0; nd < 4; ++nd)
                o[nd][r] *= a;
        }

        // O += P.V  (A=P m=i, B=V n=dd)
        const b16x8 pa0 = *(const b16x8*)(p_s + (wi0 + lo) * 64 + ((quad) ^ lsw) * 8);
        const b16x8 pa1 = *(const b16x8*)(p_s + (wi0 + lo) * 64 + ((4 + quad) ^ lsw) * 8);
        #pragma unroll
        for (int nd = 0; nd < 4; ++nd) {
            const int vr = nd * 16 + lo;
            const b16x8 vb0 = *(const b16x8*)(v_s + vr * 64 + ((quad) ^ lsw) * 8);
            const b16x8 vb1 = *(const b16x8*)(v_s + vr * 64 + ((4 + quad) ^ lsw) * 8);
            o[nd] = MFMA(pa0, vb0, o[nd]);
            o[nd] = MFMA(pa1, vb1, o[nd]);
        }
    }

    // rel-v: O += exp(band - m_fin) . erv
    {
        union { b16x8 v; u16 s[8]; } tb;
        #pragma unroll
        for (int r = 0; r < 8; ++r) {
            const int rr = quad * 8 + r;
            tb.s[r] = (rr <= 8) ? f2b(__expf(band_s[wi0 + lo][rr] - m)) : (u16)0;
        }
        const b16x8 baf = tb.v;
        #pragma unroll
        for (int nd = 0; nd < 4; ++nd) {
            union { b16x8 v; u16 s[8]; } t;
            #pragma unroll
            for (int r = 0; r < 8; ++r) {
                const int rr = quad * 8 + r;
                t.s[r] = (rr <= 8) ? f2b(erv[rr * D_ + nd * 16 + lo]) : (u16)0;
            }
            o[nd] = MFMA(baf, t.v, o[nd]);
        }
    }

    // normalize + store bf16 (B,T,C)
    if (quad == 0) alpha_s[wi0 + lo] = 1.f / l;
    #pragma unroll
    for (int r = 0; r < 4; ++r) {
        const int il = wi0 + quad * 4 + r;
        const float inv = alpha_s[il];
        const size_t base = ((size_t)b * T_ + it0 + il) * C_ + h * D_;
        #pragma unroll
        for (int nd = 0; nd < 4; ++nd)
            att[base + nd * 16 + lo] = f2b(o[nd][r] * inv);
    }
}

extern "C" void kernel_launch(void* const* d_in, const int* in_sizes, int n_in,
                              void* d_out, int out_size, void* d_ws, size_t ws_size,
                              hipStream_t stream) {
    const float* x   = (const float*)d_in[0];
    const float* w_q = (const float*)d_in[1];
    const float* b_q = (const float*)d_in[2];
    const float* w_k = (const float*)d_in[3];
    const float* b_k = (const float*)d_in[4];
    const float* w_v = (const float*)d_in[5];
    const float* b_v = (const float*)d_in[6];
    const float* w_o = (const float*)d_in[7];
    const float* b_o = (const float*)d_in[8];
    const float* erk = (const float*)d_in[9];
    const float* erv = (const float*)d_in[10];

    const size_t N = (size_t)B_ * C_ * T_;   // 3,145,728
    u16* q_ws  = (u16*)d_ws;                 // bf16 (B,H,T,d)
    u16* k_ws  = q_ws + N;                   // bf16 (B,H,T,d)
    u16* vraw  = q_ws + 2 * N;               // bf16 (B,H,T,d)   [pre-transpose]
    u16* vdT   = q_ws + 3 * N;               // bf16 (B,H,D,T)
    u16* xb    = q_ws + 4 * N;               // bf16 (B,T,C)
    u16* a_ws  = vraw;                       // bf16 (B,T,C) attn out (aliases vraw;
                                             // vraw dead once transv_kernel finishes)
    u16* wb    = q_ws + 5 * N;               // bf16 4x(C,C): wq,wk,wv,wo
    float* out = (float*)d_out;

    dim3 blk(256, 1, 1);

    convw_kernel<<<dim3(C_ * C_ / 1024, 4), blk, 0, stream>>>(w_q, w_k, w_v, w_o, wb);
    convx_kernel<<<dim3(T_ / 64, C_ / 64, B_), blk, 0, stream>>>(x, xb);

    qkv_mfma_kernel<<<dim3(T_ / 128, 18, B_), blk, 0, stream>>>(
        wb, xb, b_q, b_k, b_v, q_ws, k_ws, vraw);

    transv_kernel<<<dim3(T_ / 64, H_ * B_), blk, 0, stream>>>(vraw, vdT);

    attn_mfma_kernel<<<dim3(T_ / 64, H_, B_), blk, 0, stream>>>(
        q_ws, k_ws, vdT, erk, erv, a_ws);

    out_mfma_kernel<<<dim3(T_ / 128, C_ / 64, B_), blk, 0, stream>>>(
        wb + 3 * (size_t)C_ * C_, a_ws, b_o, out);
}

// Round 7
// 172.439 us; speedup vs baseline: 3.7933x; 1.0123x over previous
//
#include <hip/hip_runtime.h>

#define B_ 4
#define T_ 1024
#define C_ 768
#define H_ 12
#define D_ 64

typedef unsigned short u16;
typedef __attribute__((ext_vector_type(8))) short b16x8;   // 8 bf16 (4 VGPRs)
typedef __attribute__((ext_vector_type(4))) float f32x4;   // MFMA C/D

#define MFMA(a, b, c) __builtin_amdgcn_mfma_f32_16x16x32_bf16(a, b, c, 0, 0, 0)

__device__ __forceinline__ float b2f(u16 u) {
    return __uint_as_float(((unsigned)u) << 16);
}
__device__ __forceinline__ u16 f2b(float f) {
    unsigned u = __float_as_uint(f);
    u += 0x7fffu + ((u >> 16) & 1u);   // round-to-nearest-even
    return (u16)(u >> 16);
}
__device__ __forceinline__ u16 f2b_tr(float f) {    // truncate (cheap, P in [0,1])
    return (u16)(__float_as_uint(f) >> 16);
}

// async global->LDS, 16B per lane; LDS dest = wave-uniform base + lane*16
__device__ __forceinline__ void g2l16(const u16* g, u16* l) {
    __builtin_amdgcn_global_load_lds(
        (const __attribute__((address_space(1))) unsigned int*)g,
        (__attribute__((address_space(3))) unsigned int*)l, 16, 0, 0);
}

// ---------------------------------------------------------------------------
// fp32 -> bf16 weight convert (4 matrices concatenated into wb)
// ---------------------------------------------------------------------------
__global__ __launch_bounds__(256) void convw_kernel(
    const float* __restrict__ w0, const float* __restrict__ w1,
    const float* __restrict__ w2, const float* __restrict__ w3,
    u16* __restrict__ o)
{
    const float* src = blockIdx.y == 0 ? w0 : blockIdx.y == 1 ? w1 :
                       blockIdx.y == 2 ? w2 : w3;
    u16* dst = o + (size_t)blockIdx.y * C_ * C_;
    const int i = (blockIdx.x * 256 + threadIdx.x) * 4;
    float4 v = *(const float4*)(src + i);
    ushort4 st = {f2b(v.x), f2b(v.y), f2b(v.z), f2b(v.w)};
    *(ushort4*)(dst + i) = st;
}

// ---------------------------------------------------------------------------
// x (B,C,T) fp32 -> xb (B,T,C) bf16 (transpose through LDS tile)
// ---------------------------------------------------------------------------
__global__ __launch_bounds__(256) void convx_kernel(
    const float* __restrict__ x, u16* __restrict__ xb)
{
    __shared__ u16 tile[64][68];
    const int tid = threadIdx.x;
    const int t0 = blockIdx.x * 64, c0 = blockIdx.y * 64, b = blockIdx.z;
    #pragma unroll
    for (int p = 0; p < 4; ++p) {
        const int cc = p * 16 + (tid >> 4);
        const int t4 = (tid & 15) * 4;
        float4 v = *(const float4*)(x + ((size_t)b * C_ + c0 + cc) * T_ + t0 + t4);
        tile[t4 + 0][cc] = f2b(v.x);
        tile[t4 + 1][cc] = f2b(v.y);
        tile[t4 + 2][cc] = f2b(v.z);
        tile[t4 + 3][cc] = f2b(v.w);
    }
    __syncthreads();
    #pragma unroll
    for (int p = 0; p < 4; ++p) {
        const int tt = p * 16 + (tid >> 4);
        const int c4 = (tid & 15) * 4;
        ushort4 st = *(const ushort4*)&tile[tt][c4];
        *(ushort4*)(xb + ((size_t)b * T_ + t0 + tt) * C_ + c0 + c4) = st;
    }
}

// ---------------------------------------------------------------------------
// Fused QKV projection, MFMA bf16, BK=64 (12 barrier-pairs instead of 24).
// Tile 128(o) x 128(t). LDS rows stride 64 u16 = 128 B, 8-chunk XOR swizzle.
// ---------------------------------------------------------------------------
__global__ __launch_bounds__(256) void qkv_mfma_kernel(
    const u16* __restrict__ wb, const u16* __restrict__ xb,
    const float* __restrict__ b_q, const float* __restrict__ b_k,
    const float* __restrict__ b_v,
    u16* __restrict__ q_ws, u16* __restrict__ k_ws, u16* __restrict__ v_ws)
{
    __shared__ __align__(16) u16 a_s[128 * 64];
    __shared__ __align__(16) u16 b_s[128 * 64];

    const int tid = threadIdx.x;
    const int wv = tid >> 6, lane = tid & 63;
    const int lo = lane & 15, quad = lane >> 4;
    const int wm = wv >> 1, wn = wv & 1;
    const int lsw = lo & 7;                        // read-side swizzle key
    const int srow = lane >> 3;                    // staging row within instr
    const int schunk = (lane & 7) ^ srow;          // swizzled source chunk

    const int t0 = blockIdx.x * 128;
    const int mat = blockIdx.y / 6, oy = blockIdx.y % 6;
    const int o0 = oy * 128;
    const int b  = blockIdx.z;

    const u16* A = wb + (size_t)mat * C_ * C_;
    const float* bias = mat == 0 ? b_q : (mat == 1 ? b_k : b_v);
    u16* dst = mat == 0 ? q_ws : (mat == 1 ? k_ws : v_ws);
    const float scale = mat == 0 ? 0.125f : 1.0f;

    const size_t bT0 = (size_t)b * T_ + t0;

    f32x4 acc[4][4] = {};

    for (int kk = 0; kk < C_; kk += 64) {
        __syncthreads();
        #pragma unroll
        for (int ia = 0; ia < 4; ++ia) {           // A: 16 instrs, 4/wave
            const int row0 = (wv * 4 + ia) * 8;
            g2l16(A + (size_t)(o0 + row0 + srow) * C_ + kk + schunk * 8,
                  a_s + row0 * 64);
        }
        #pragma unroll
        for (int ib = 0; ib < 4; ++ib) {           // B: 16 instrs, 4/wave
            const int row0 = (wv * 4 + ib) * 8;
            g2l16(xb + (bT0 + row0 + srow) * C_ + kk + schunk * 8,
                  b_s + row0 * 64);
        }
        __syncthreads();

        #pragma unroll
        for (int kc = 0; kc < 2; ++kc) {
            const int slotk = kc * 4;
            b16x8 af[4], bf[4];
            #pragma unroll
            for (int mi = 0; mi < 4; ++mi) {
                const int m = wm * 64 + mi * 16 + lo;
                af[mi] = *(const b16x8*)(a_s + m * 64 + ((slotk + quad) ^ lsw) * 8);
            }
            #pragma unroll
            for (int ni = 0; ni < 4; ++ni) {
                const int n = wn * 64 + ni * 16 + lo;
                bf[ni] = *(const b16x8*)(b_s + n * 64 + ((slotk + quad) ^ lsw) * 8);
            }
            #pragma unroll
            for (int mi = 0; mi < 4; ++mi)
                #pragma unroll
                for (int ni = 0; ni < 4; ++ni)
                    acc[mi][ni] = MFMA(af[mi], bf[ni], acc[mi][ni]);
        }
    }

    #pragma unroll
    for (int mi = 0; mi < 4; ++mi) {
        const int o_b = o0 + wm * 64 + mi * 16 + quad * 4;
        const float4 bv4 = *(const float4*)(bias + o_b);
        const int h = o_b >> 6;
        const int dd0 = o_b & 63;
        #pragma unroll
        for (int ni = 0; ni < 4; ++ni) {
            const int t = t0 + wn * 64 + ni * 16 + lo;
            f32x4 a = acc[mi][ni];
            ushort4 st;
            st.x = f2b((a[0] + bv4.x) * scale);
            st.y = f2b((a[1] + bv4.y) * scale);
            st.z = f2b((a[2] + bv4.z) * scale);
            st.w = f2b((a[3] + bv4.w) * scale);
            *(ushort4*)(dst + (((size_t)b * H_ + h) * T_ + t) * D_ + dd0) = st;
        }
    }
}

// ---------------------------------------------------------------------------
// v (B,H,T,d) bf16 -> (B,H,D,T) bf16 (transpose through LDS tile)
// ---------------------------------------------------------------------------
__global__ __launch_bounds__(256) void transv_kernel(
    const u16* __restrict__ src, u16* __restrict__ dst)
{
    __shared__ __align__(16) u16 tile[64 * 72];
    const int tid = threadIdx.x;
    const int t0 = blockIdx.x * 64;
    const int bh = blockIdx.y;
    const u16* s = src + (size_t)bh * T_ * D_;
    u16* d = dst + (size_t)bh * D_ * T_;
    #pragma unroll
    for (int p = 0; p < 2; ++p) {
        const int idx = tid + p * 256;
        const int row = idx >> 3, ch = idx & 7;
        *(b16x8*)(tile + row * 72 + ch * 8) =
            *(const b16x8*)(s + (size_t)(t0 + row) * D_ + ch * 8);
    }
    __syncthreads();
    #pragma unroll
    for (int p = 0; p < 2; ++p) {
        const int idx = tid + p * 256;
        const int dd = idx >> 3, ch = idx & 7;
        union { b16x8 v; u16 e[8]; } t;
        #pragma unroll
        for (int e = 0; e < 8; ++e)
            t.e[e] = tile[(ch * 8 + e) * 72 + dd];
        *(b16x8*)(d + (size_t)dd * T_ + t0 + ch * 8) = t.v;
    }
}

// ---------------------------------------------------------------------------
// Output projection, MFMA bf16, BK=64 (6 barrier-pairs). Tile 64(o) x 128(t).
// ---------------------------------------------------------------------------
__global__ __launch_bounds__(256) void out_mfma_kernel(
    const u16* __restrict__ wob, const u16* __restrict__ ab,
    const float* __restrict__ bias, float* __restrict__ out)
{
    __shared__ __align__(16) u16 a_s[64 * 64];
    __shared__ __align__(16) u16 b_s[128 * 64];

    const int tid = threadIdx.x;
    const int wv = tid >> 6, lane = tid & 63;
    const int lo = lane & 15, quad = lane >> 4;
    const int wm = wv >> 1, wn = wv & 1;
    const int lsw = lo & 7;
    const int srow = lane >> 3;
    const int schunk = (lane & 7) ^ srow;

    const int t0 = blockIdx.x * 128;
    const int o0 = blockIdx.y * 64;
    const int b  = blockIdx.z;
    const size_t bT0 = (size_t)b * T_ + t0;

    f32x4 acc[2][4] = {};

    for (int kk = 0; kk < C_; kk += 64) {
        __syncthreads();
        #pragma unroll
        for (int ia = 0; ia < 2; ++ia) {          // A: 8 instrs, 2/wave
            const int row0 = (wv * 2 + ia) * 8;
            g2l16(wob + (size_t)(o0 + row0 + srow) * C_ + kk + schunk * 8,
                  a_s + row0 * 64);
        }
        #pragma unroll
        for (int ib = 0; ib < 4; ++ib) {          // B: 16 instrs, 4/wave
            const int row0 = (wv * 4 + ib) * 8;
            g2l16(ab + (bT0 + row0 + srow) * C_ + kk + schunk * 8,
                  b_s + row0 * 64);
        }
        __syncthreads();

        #pragma unroll
        for (int kc = 0; kc < 2; ++kc) {
            const int slotk = kc * 4;
            b16x8 af[2], bf[4];
            #pragma unroll
            for (int mi = 0; mi < 2; ++mi) {
                const int m = wm * 32 + mi * 16 + lo;
                af[mi] = *(const b16x8*)(a_s + m * 64 + ((slotk + quad) ^ lsw) * 8);
            }
            #pragma unroll
            for (int ni = 0; ni < 4; ++ni) {
                const int n = wn * 64 + ni * 16 + lo;
                bf[ni] = *(const b16x8*)(b_s + n * 64 + ((slotk + quad) ^ lsw) * 8);
            }
            #pragma unroll
            for (int mi = 0; mi < 2; ++mi)
                #pragma unroll
                for (int ni = 0; ni < 4; ++ni)
                    acc[mi][ni] = MFMA(af[mi], bf[ni], acc[mi][ni]);
        }
    }

    #pragma unroll
    for (int mi = 0; mi < 2; ++mi) {
        const int o_b = o0 + wm * 32 + mi * 16 + quad * 4;
        const float4 bv4 = *(const float4*)(bias + o_b);
        const float bb[4] = {bv4.x, bv4.y, bv4.z, bv4.w};
        #pragma unroll
        for (int ni = 0; ni < 4; ++ni) {
            const int t = t0 + wn * 64 + ni * 16 + lo;
            f32x4 a = acc[mi][ni];
            #pragma unroll
            for (int r = 0; r < 4; ++r)
                out[((size_t)b * C_ + o_b + r) * T_ + t] = a[r] + bb[r];
        }
    }
}

// ---------------------------------------------------------------------------
// MFMA flash attention, 32-row Q blocks (2 waves x 16 rows), grid 32x12x4 =
// 1536 blocks (~6 blocks/CU -> fine-grained barriers). Band bias applied only
// on the <=2 j-tiles that intersect the +-4 window (wave-uniform hoist).
// ---------------------------------------------------------------------------
__global__ __launch_bounds__(128, 4) void attn_mfma_kernel(
    const u16* __restrict__ qw, const u16* __restrict__ kw, const u16* __restrict__ vw,
    const float* __restrict__ erk, const float* __restrict__ erv,
    u16* __restrict__ att)
{
    __shared__ __align__(16) u16 k_s[64 * 64];   // [j][d], 16B chunks XOR-swizzled
    __shared__ __align__(16) u16 v_s[64 * 64];   // [dd][j], swizzled
    __shared__ __align__(16) u16 p_s[32 * 64];   // [i][j], swizzled
    __shared__ float qrel_s[32][9];
    __shared__ float band_s[32][9];
    __shared__ float alpha_s[32];

    const int tid = threadIdx.x;
    const int wv = tid >> 6, lane = tid & 63;
    const int lo = lane & 15, quad = lane >> 4;
    const int wi0 = wv * 16;
    const int it0 = blockIdx.x * 32;
    const int h = blockIdx.y, b = blockIdx.z;
    const int bh = b * H_ + h;

    const u16* qp = qw + (size_t)bh * T_ * D_;
    const u16* kp = kw + (size_t)bh * T_ * D_;
    const u16* vp = vw + (size_t)bh * D_ * T_;

    const int srow = lane >> 3;
    const int schunk = (lane & 7) ^ srow;
    const int lsw = lo & 7;

    // Q frags: row i = it0+wi0+lo, k = kc*32+quad*8
    b16x8 qf[2];
    #pragma unroll
    for (int kc = 0; kc < 2; ++kc)
        qf[kc] = *(const b16x8*)(qp + (size_t)(it0 + wi0 + lo) * D_ + kc * 32 + quad * 8);

    // qrel[i][r] = q_i . erk_r via MFMA (A=Q, B=erk)
    {
        b16x8 ekf[2];
        #pragma unroll
        for (int kc = 0; kc < 2; ++kc) {
            union { b16x8 v; u16 s[8]; } t;
            #pragma unroll
            for (int r = 0; r < 8; ++r) t.s[r] = 0;
            if (lo < 9) {
                const float* e = erk + lo * D_ + kc * 32 + quad * 8;
                #pragma unroll
                for (int r = 0; r < 8; ++r) t.s[r] = f2b(e[r]);
            }
            ekf[kc] = t.v;
        }
        f32x4 acc = {};
        acc = MFMA(qf[0], ekf[0], acc);
        acc = MFMA(qf[1], ekf[1], acc);
        if (lo < 9)
            #pragma unroll
            for (int r = 0; r < 4; ++r)
                qrel_s[wi0 + quad * 4 + r][lo] = acc[r];
    }

    // band init (wave-local rows only -> no barrier needed)
    for (int idx = lane; idx < 16 * 9; idx += 64)
        band_s[wi0 + idx / 9][idx % 9] = -1e30f;

    f32x4 o[4] = {};
    float m = -1e30f, l = 0.f;

    for (int jt = 0; jt < T_; jt += 64) {
        __syncthreads();
        #pragma unroll
        for (int i2 = 0; i2 < 4; ++i2) {
            const int row0 = (wv * 4 + i2) * 8;
            g2l16(kp + (size_t)(jt + row0 + srow) * D_ + schunk * 8, k_s + row0 * 64);
            g2l16(vp + (size_t)(row0 + srow) * T_ + jt + schunk * 8, v_s + row0 * 64);
        }
        __syncthreads();

        // S^T: A=K (m=j), B=Q (n=i)
        f32x4 st[4];
        #pragma unroll
        for (int mt = 0; mt < 4; ++mt) {
            const int kr = mt * 16 + lo;
            const b16x8 ka0 = *(const b16x8*)(k_s + kr * 64 + ((quad) ^ lsw) * 8);
            const b16x8 ka1 = *(const b16x8*)(k_s + kr * 64 + ((4 + quad) ^ lsw) * 8);
            f32x4 a = {};
            a = MFMA(ka0, qf[0], a);
            a = MFMA(ka1, qf[1], a);
            st[mt] = a;
        }

        // windowed rel-k bias + band capture — only <=2 of 16 tiles intersect
        if (jt >= it0 - 67 && jt <= it0 + 35) {
            const int ibase = it0 + wi0 + lo;
            #pragma unroll
            for (int mt = 0; mt < 4; ++mt)
                #pragma unroll
                for (int r = 0; r < 4; ++r) {
                    const int rr = (jt + mt * 16 + quad * 4 + r) - ibase + 4;
                    if (rr >= 0 && rr <= 8) {
                        const float s2 = st[mt][r] + qrel_s[wi0 + lo][rr];
                        st[mt][r] = s2;
                        band_s[wi0 + lo][rr] = s2;
                    }
                }
        }

        // online softmax per column i (reduce across quads)
        float tm = -1e30f;
        #pragma unroll
        for (int mt = 0; mt < 4; ++mt)
            #pragma unroll
            for (int r = 0; r < 4; ++r)
                tm = fmaxf(tm, st[mt][r]);
        tm = fmaxf(tm, __shfl_xor(tm, 16));
        tm = fmaxf(tm, __shfl_xor(tm, 32));
        const float nm = fmaxf(m, tm);
        const float al = __expf(m - nm);
        m = nm;
        float rs = 0.f;
        #pragma unroll
        for (int mt = 0; mt < 4; ++mt)
            #pragma unroll
            for (int r = 0; r < 4; ++r) {
                const float e = __expf(st[mt][r] - nm);
                st[mt][r] = e;
                rs += e;
            }
        rs += __shfl_xor(rs, 16);
        rs += __shfl_xor(rs, 32);
        l = l * al + rs;
        if (quad == 0) alpha_s[wi0 + lo] = al;

        // P -> LDS (wave-local rows), truncating pack, swizzled chunks
        #pragma unroll
        for (int mt = 0; mt < 4; ++mt) {
            ushort4 pw;
            pw.x = f2b_tr(st[mt][0]);
            pw.y = f2b_tr(st[mt][1]);
            pw.z = f2b_tr(st[mt][2]);
            pw.w = f2b_tr(st[mt][3]);
            const int slot = (mt * 2 + (quad >> 1)) ^ lsw;
            *(ushort4*)(p_s + (wi0 + lo) * 64 + slot * 8 + (quad & 1) * 4) = pw;
        }

        // rescale O rows (row i = wi0 + quad*4 + r)
        #pragma unroll
        for (int r = 0; r < 4; ++r) {
            const float a = alpha_s[wi0 + quad * 4 + r];
            #pragma unroll
            for (int nd = 0; nd < 4; ++nd)
                o[nd][r] *= a;
        }

        // O += P.V  (A=P m=i, B=V n=dd)
        const b16x8 pa0 = *(const b16x8*)(p_s + (wi0 + lo) * 64 + ((quad) ^ lsw) * 8);
        const b16x8 pa1 = *(const b16x8*)(p_s + (wi0 + lo) * 64 + ((4 + quad) ^ lsw) * 8);
        #pragma unroll
        for (int nd = 0; nd < 4; ++nd) {
            const int vr = nd * 16 + lo;
            const b16x8 vb0 = *(const b16x8*)(v_s + vr * 64 + ((quad) ^ lsw) * 8);
            const b16x8 vb1 = *(const b16x8*)(v_s + vr * 64 + ((4 + quad) ^ lsw) * 8);
            o[nd] = MFMA(pa0, vb0, o[nd]);
            o[nd] = MFMA(pa1, vb1, o[nd]);
        }
    }

    // rel-v: O += exp(band - m_fin) . erv
    {
        union { b16x8 v; u16 s[8]; } tb;
        #pragma unroll
        for (int r = 0; r < 8; ++r) {
            const int rr = quad * 8 + r;
            tb.s[r] = (rr <= 8) ? f2b(__expf(band_s[wi0 + lo][rr] - m)) : (u16)0;
        }
        const b16x8 baf = tb.v;
        #pragma unroll
        for (int nd = 0; nd < 4; ++nd) {
            union { b16x8 v; u16 s[8]; } t;
            #pragma unroll
            for (int r = 0; r < 8; ++r) {
                const int rr = quad * 8 + r;
                t.s[r] = (rr <= 8) ? f2b(erv[rr * D_ + nd * 16 + lo]) : (u16)0;
            }
            o[nd] = MFMA(baf, t.v, o[nd]);
        }
    }

    // normalize + store bf16 (B,T,C)
    if (quad == 0) alpha_s[wi0 + lo] = 1.f / l;
    #pragma unroll
    for (int r = 0; r < 4; ++r) {
        const int il = wi0 + quad * 4 + r;
        const float inv = alpha_s[il];
        const size_t base = ((size_t)b * T_ + it0 + il) * C_ + h * D_;
        #pragma unroll
        for (int nd = 0; nd < 4; ++nd)
            att[base + nd * 16 + lo] = f2b(o[nd][r] * inv);
    }
}

extern "C" void kernel_launch(void* const* d_in, const int* in_sizes, int n_in,
                              void* d_out, int out_size, void* d_ws, size_t ws_size,
                              hipStream_t stream) {
    const float* x   = (const float*)d_in[0];
    const float* w_q = (const float*)d_in[1];
    const float* b_q = (const float*)d_in[2];
    const float* w_k = (const float*)d_in[3];
    const float* b_k = (const float*)d_in[4];
    const float* w_v = (const float*)d_in[5];
    const float* b_v = (const float*)d_in[6];
    const float* w_o = (const float*)d_in[7];
    const float* b_o = (const float*)d_in[8];
    const float* erk = (const float*)d_in[9];
    const float* erv = (const float*)d_in[10];

    const size_t N = (size_t)B_ * C_ * T_;   // 3,145,728
    u16* q_ws  = (u16*)d_ws;                 // bf16 (B,H,T,d)
    u16* k_ws  = q_ws + N;                   // bf16 (B,H,T,d)
    u16* vraw  = q_ws + 2 * N;               // bf16 (B,H,T,d)   [pre-transpose]
    u16* vdT   = q_ws + 3 * N;               // bf16 (B,H,D,T)
    u16* xb    = q_ws + 4 * N;               // bf16 (B,T,C)
    u16* a_ws  = vraw;                       // bf16 (B,T,C) attn out (aliases vraw;
                                             // vraw dead once transv_kernel finishes)
    u16* wb    = q_ws + 5 * N;               // bf16 4x(C,C): wq,wk,wv,wo
    float* out = (float*)d_out;

    dim3 blk(256, 1, 1);

    convw_kernel<<<dim3(C_ * C_ / 1024, 4), blk, 0, stream>>>(w_q, w_k, w_v, w_o, wb);
    convx_kernel<<<dim3(T_ / 64, C_ / 64, B_), blk, 0, stream>>>(x, xb);

    qkv_mfma_kernel<<<dim3(T_ / 128, 18, B_), blk, 0, stream>>>(
        wb, xb, b_q, b_k, b_v, q_ws, k_ws, vraw);

    transv_kernel<<<dim3(T_ / 64, H_ * B_), blk, 0, stream>>>(vraw, vdT);

    attn_mfma_kernel<<<dim3(T_ / 32, H_, B_), dim3(128, 1, 1), 0, stream>>>(
        q_ws, k_ws, vdT, erk, erv, a_ws);

    out_mfma_kernel<<<dim3(T_ / 128, C_ / 64, B_), blk, 0, stream>>>(
        wb + 3 * (size_t)C_ * C_, a_ws, b_o, out);
}